// Round 14
// baseline (108.046 us; speedup 1.0000x reference)
//
#include <hip/hip_runtime.h>

#define EPS 1e-3f

typedef _Float16 half8 __attribute__((ext_vector_type(8)));
typedef _Float16 half4v __attribute__((ext_vector_type(4)));
typedef float f32x4 __attribute__((ext_vector_type(4)));

// ---------------------------------------------------------------------------
// Merged weight prep (single dispatch), branch by block range (unchanged r13).
// ---------------------------------------------------------------------------
__global__ __launch_bounds__(256) void k_wprep_all(
    const float* __restrict__ dW,  _Float16* __restrict__ Wt2,
    const float* __restrict__ eW1, _Float16* __restrict__ eW1t,
    const float* __restrict__ eW2, _Float16* __restrict__ eW2t,
    const float* __restrict__ cW1, _Float16* __restrict__ Wt1,
    const float* __restrict__ cW2, _Float16* __restrict__ Wt,
    const float* __restrict__ eW3, _Float16* __restrict__ eW3p)
{
    __shared__ _Float16 lsbuf[16640];
    int bx = blockIdx.x, tid = threadIdx.x;

    if (bx < 64) {
        auto lt = (_Float16(*)[137])lsbuf;       // [64][137]
        int kb = bx * 64;
        int c = tid & 127, r2 = tid >> 7;
#pragma unroll
        for (int it = 0; it < 32; ++it) {
            int r = it * 2 + r2;
            lt[r][c] = (_Float16)dW[(long)(kb + r) * 128 + c];
        }
        __syncthreads();
#pragma unroll
        for (int it = 0; it < 4; ++it) {
            int chunk = it * 256 + tid;
            int n = chunk >> 3, kc = (chunk & 7) * 8;
            half8 v;
#pragma unroll
            for (int j = 0; j < 8; ++j) v[j] = lt[kc + j][n];
            *(half8*)(Wt2 + (long)n * 4096 + kb + kc) = v;
        }
    } else if (bx < 80) {
        auto lt = (_Float16(*)[130])lsbuf;       // [128][130]
        int e = bx - 64;
        const float* src = eW1 + (long)e * 16384;
#pragma unroll
        for (int it = 0; it < 64; ++it) {
            int idx = it * 256 + tid;
            lt[idx >> 7][idx & 127] = (_Float16)src[idx];
        }
        __syncthreads();
        _Float16* dst = eW1t + (long)e * 16384;
#pragma unroll
        for (int it = 0; it < 64; ++it) {
            int idx = it * 256 + tid;            // idx = h*128 + d
            dst[idx] = lt[idx & 127][idx >> 7];
        }
    } else if (bx < 96) {
        auto lt = (_Float16(*)[66])lsbuf;        // [128][66]
        int e = bx - 80;
        const float* src = eW2 + (long)e * 8192;
#pragma unroll
        for (int it = 0; it < 32; ++it) {
            int idx = it * 256 + tid;
            lt[idx >> 6][idx & 63] = (_Float16)src[idx];
        }
        __syncthreads();
        _Float16* dst = eW2t + (long)e * 8192;
#pragma unroll
        for (int it = 0; it < 32; ++it) {
            int idx = it * 256 + tid;            // idx = n*128 + d
            dst[idx] = lt[idx & 127][idx >> 7];
        }
    } else {
        int t = (bx - 96) * 256 + tid;
        if (t < 2048) {
            int k = t & 31, co = (t >> 5) & 31, p = t >> 10;
            int kyin = (k >> 4) & 1, kxp = (k >> 2) & 3, ci = k & 3;
            int ky = 2 * p + kyin;
            float val = (ky < 3 && kxp < 3 && ci < 3)
                        ? cW1[((ky * 3 + kxp) * 3 + ci) * 32 + co] : 0.f;
            Wt1[t] = (_Float16)val;
        } else if (t >= 3072 && t < 3072 + 18432) {
            int u = t - 3072;
            int co = u & 63;
            int rest = u >> 6;
            int ci = rest & 31, tap = rest >> 5;
            Wt[(tap * 64 + co) * 32 + ci] = (_Float16)cW2[u];
        } else if (t >= 21504 && t < 21504 + 16384) {
            int u = t - 21504;
            int k = u & 63, n = (u >> 6) & 15, e = u >> 10;
            float val = (n < 10) ? eW3[(e * 64 + k) * 10 + n] : 0.f;
            eW3p[(e * 16 + n) * 64 + k] = (_Float16)val;
        }
    }
}

// ---------------------------------------------------------------------------
// Fused conv1+conv2, f16 MFMA — HALF-IMAGE blocks for 2x occupancy.
// Grid (2048 images, 2 halves). LDS 20.4 KB -> 7-8 blocks/CU.
// Phase A: compute 9 pooled h1 rows (7h..7h+8; rows 7/8 overlap-computed by
//   both halves) -> As2 [10][18][40] (h1 rows 8h-1..8h+8, halos zero).
// Phase B: conv2 pre-pool rows 8h..8h+7, wave w owns 2 rows -> 1 pooled row.
// ---------------------------------------------------------------------------
__global__ __launch_bounds__(256) void k_conv12(
    const float* __restrict__ x, const _Float16* __restrict__ Wt1,
    const float* __restrict__ b1, const float* __restrict__ g1,
    const float* __restrict__ bb1, const float* __restrict__ m1,
    const float* __restrict__ v1,
    const _Float16* __restrict__ Wt,
    const float* __restrict__ b2, const float* __restrict__ g2,
    const float* __restrict__ bb2, const float* __restrict__ m2,
    const float* __restrict__ v2,
    _Float16* __restrict__ out)
{
    __shared__ __align__(16) _Float16 As1[21][36][4];   // input rows gstart..gstart+19 (+row20 overread, zero)
    __shared__ __align__(16) _Float16 As2[10][18][40];  // h1 rows 8h-1..8h+8
    int tid = threadIdx.x;
    int b  = blockIdx.x;
    int hh = blockIdx.y;                 // image half 0/1
    int w = tid >> 6, l = tid & 63;
    int l15 = l & 15, lq = l >> 4;
    int lqr = lq >> 1, lqc = (lq & 1) * 2;
    int start  = 7 * hh;                 // first computed pooled h1 row
    int gstart = 14 * hh - 1;            // first staged input row

    // zero LDS (halos + overread row + pads must be 0)
    {
        float4 z = make_float4(0.f, 0.f, 0.f, 0.f);
        float4* f1p = (float4*)&As1[0][0][0];
        for (int i = tid; i < 378; i += 256) f1p[i] = z;     // 21*36*4 f16
        float4* f2p = (float4*)&As2[0][0][0];
        for (int i = tid; i < 900; i += 256) f2p[i] = z;     // 10*18*40 f16
    }
    __syncthreads();

    // stage 20 input rows x 32 px (3 floats each; boundary rows stay zero)
    for (int i = tid; i < 640; i += 256) {
        int row = i >> 5, px = i & 31;
        int g = gstart + row;
        if ((unsigned)g < 32u) {
            const float* src = x + ((long)b * 1024 + g * 32 + px) * 3;
            half4v hv = { (_Float16)src[0], (_Float16)src[1], (_Float16)src[2], (_Float16)0.f };
            *(half4v*)&As1[row][px + 1][0] = hv;
        }
    }

    // conv1 B-frags (ky-paired) + BN S/T consts
    half8 bf1[2][2];
#pragma unroll
    for (int p = 0; p < 2; ++p)
#pragma unroll
        for (int nf = 0; nf < 2; ++nf)
            bf1[p][nf] = *(const half8*)(Wt1 + (p * 32 + nf * 16 + l15) * 32 + lq * 8);

    float bv1[2], S1[2], T1[2];
#pragma unroll
    for (int nf = 0; nf < 2; ++nf) {
        int co = nf * 16 + l15;
        bv1[nf] = b1[co];
        float s = rsqrtf(v1[co] + EPS) * g1[co];
        S1[nf] = s;
        T1[nf] = bb1[co] - m1[co] * s;
    }
    __syncthreads();

    // ---- Phase A: 9 pooled h1 rows q=0..8 split 3/2/2/2 across waves ----
    {
        int qstart = (w == 0) ? 0 : (2 * w + 1);
        int qcnt   = (w == 0) ? 3 : 2;
        for (int qq = 0; qq < qcnt; ++qq) {
            int q = qstart + qq;            // pooled row: h1 global row start+q
            f32x4 acc[2][2][2];             // [pre-pool r][x-half xh][nf]
#pragma unroll
            for (int r = 0; r < 2; ++r)
#pragma unroll
                for (int xh = 0; xh < 2; ++xh)
#pragma unroll
                    for (int nf = 0; nf < 2; ++nf)
                        acc[r][xh][nf] = (f32x4){ bv1[nf], bv1[nf], bv1[nf], bv1[nf] };

#pragma unroll
            for (int p = 0; p < 2; ++p)
#pragma unroll
                for (int r = 0; r < 2; ++r)
#pragma unroll
                    for (int xh = 0; xh < 2; ++xh) {
                        // local pre-pool row Yl = 2q+r ; As1 row = Yl + 2p + lqr
                        const _Float16* ap = &As1[2 * q + r + 2 * p + lqr][xh * 16 + l15 + lqc][0];
                        half4v a0 = *(const half4v*)ap;
                        half4v a1 = *(const half4v*)(ap + 4);
                        half8 af = __builtin_shufflevector(a0, a1, 0, 1, 2, 3, 4, 5, 6, 7);
#pragma unroll
                        for (int nf = 0; nf < 2; ++nf)
                            acc[r][xh][nf] = __builtin_amdgcn_mfma_f32_16x16x32_f16(
                                af, bf1[p][nf], acc[r][xh][nf], 0, 0, 0);
                    }

            int a2row = q + 1 - hh;         // As2 row for h1 row start+q
#pragma unroll
            for (int xh = 0; xh < 2; ++xh)
#pragma unroll
                for (int nf = 0; nf < 2; ++nf) {
                    f32x4 aA = acc[0][xh][nf], aB = acc[1][xh][nf];
                    float p0 = fmaxf(fmaxf(aA[0], aA[1]), fmaxf(aB[0], aB[1]));
                    float p1 = fmaxf(fmaxf(aA[2], aA[3]), fmaxf(aB[2], aB[3]));
                    p0 = fmaxf(p0, 0.f); p1 = fmaxf(p1, 0.f);
                    p0 = fmaf(p0, S1[nf], T1[nf]);
                    p1 = fmaf(p1, S1[nf], T1[nf]);
                    int px = xh * 8 + lq * 2;
                    int co = nf * 16 + l15;
                    As2[a2row][px + 1][co] = (_Float16)p0;
                    As2[a2row][px + 2][co] = (_Float16)p1;
                }
        }
    }
    __syncthreads();

    // ---- Phase B: conv2 local pre-pool rows yb = 2w, 2w+1 -> pooled row w ----
    f32x4 acc2[2][4];
#pragma unroll
    for (int nf = 0; nf < 4; ++nf) {
        float bv = b2[nf * 16 + l15];
#pragma unroll
        for (int mf = 0; mf < 2; ++mf)
            acc2[mf][nf] = (f32x4){ bv, bv, bv, bv };
    }

#pragma unroll
    for (int tap = 0; tap < 9; ++tap) {
        int ky = tap / 3, kx = tap % 3;
        half8 bf[4];
        const _Float16* wb = Wt + ((long)(tap * 64 + l15)) * 32 + lq * 8;
#pragma unroll
        for (int nf = 0; nf < 4; ++nf)
            bf[nf] = *(const half8*)(wb + (long)nf * 16 * 32);
#pragma unroll
        for (int mf = 0; mf < 2; ++mf) {
            const _Float16* ap = &As2[2 * w + mf + ky][l15 + kx][lq * 8];
            half8 af = *(const half8*)ap;
#pragma unroll
            for (int nf = 0; nf < 4; ++nf)
                acc2[mf][nf] = __builtin_amdgcn_mfma_f32_16x16x32_f16(
                    af, bf[nf], acc2[mf][nf], 0, 0, 0);
        }
    }

    {
        int prow = hh * 4 + w;              // global pooled h2 row
#pragma unroll
        for (int nf = 0; nf < 4; ++nf) {
            int co = nf * 16 + l15;
            float s = rsqrtf(v2[co] + EPS) * g2[co];
            float t2 = bb2[co] - m2[co] * s;
            f32x4 a0 = acc2[0][nf];
            f32x4 a1 = acc2[1][nf];
            float p0 = fmaxf(fmaxf(a0[0], a0[1]), fmaxf(a1[0], a1[1]));
            float p1 = fmaxf(fmaxf(a0[2], a0[3]), fmaxf(a1[2], a1[3]));
            p0 = fmaxf(p0, 0.f);
            p1 = fmaxf(p1, 0.f);
            int ppx = lq * 2;
            long base = (((long)b * 8 + prow) * 8) * 64 + co;
            out[base + (long)(ppx    ) * 64] = (_Float16)fmaf(p0, s, t2);
            out[base + (long)(ppx + 1) * 64] = (_Float16)fmaf(p1, s, t2);
        }
    }
}

// ---------------------------------------------------------------------------
// Kernel 3a: dense 4096 -> 128, split-K x8, f16 MFMA. (unchanged)
// ---------------------------------------------------------------------------
__global__ __launch_bounds__(256) void k_dense_mfma(
    const _Float16* __restrict__ h2f, const _Float16* __restrict__ Wt2,
    float* __restrict__ pws)
{
    __shared__ __align__(16) _Float16 As[16][264];
    int tid = threadIdx.x;
    int w = tid >> 6, l = tid & 63;
    int l15 = l & 15, lq = l >> 4;
    int brow = blockIdx.x * 16;
    int kbase = blockIdx.y * 512;
    int n0 = w * 32;

    f32x4 acc[2] = { (f32x4){0.f,0.f,0.f,0.f}, (f32x4){0.f,0.f,0.f,0.f} };

    int srow = tid >> 4, sc = (tid & 15) * 16;
#pragma unroll
    for (int k0 = 0; k0 < 512; k0 += 256) {
        __syncthreads();
        const _Float16* src = h2f + (long)(brow + srow) * 4096 + kbase + k0 + sc;
        half8 v0 = *(const half8*)src;
        half8 v1 = *(const half8*)(src + 8);
        *(half8*)(&As[srow][sc])     = v0;
        *(half8*)(&As[srow][sc + 8]) = v1;
        __syncthreads();
#pragma unroll
        for (int kk = 0; kk < 256; kk += 32) {
            half8 af = *(const half8*)(&As[l15][kk + lq * 8]);
#pragma unroll
            for (int nf = 0; nf < 2; ++nf) {
                half8 bf = *(const half8*)(Wt2 + (long)(n0 + nf * 16 + l15) * 4096
                                           + kbase + k0 + kk + lq * 8);
                acc[nf] = __builtin_amdgcn_mfma_f32_16x16x32_f16(af, bf, acc[nf], 0, 0, 0);
            }
        }
    }

    float* pbase = pws + (long)blockIdx.y * 262144;
#pragma unroll
    for (int nf = 0; nf < 2; ++nf) {
        int n = n0 + nf * 16 + l15;
#pragma unroll
        for (int reg = 0; reg < 4; ++reg) {
            int b = brow + lq * 4 + reg;
            pbase[(long)b * 128 + n] = acc[nf][reg];
        }
    }
}

// ---------------------------------------------------------------------------
// Kernel 3b: fused split-K reduce + bias + relu -> featsH, then router MLP
// + softmax. One block per 8 batch rows (grid 256). (unchanged r13)
// ---------------------------------------------------------------------------
__global__ __launch_bounds__(256) void k_reduce_router(
    const float* __restrict__ pws, const float* __restrict__ db,
    const float* __restrict__ rW1, const float* __restrict__ rb1,
    const float* __restrict__ rW2, const float* __restrict__ rb2,
    _Float16* __restrict__ featsH, float* __restrict__ probs)
{
    __shared__ float fsm[8][128];
    __shared__ float r1s[8][64];
    int tid = threadIdx.x;
    int brow = blockIdx.x * 8;
    int r = tid >> 5, c0 = (tid & 31) * 4;

    float acc[4];
#pragma unroll
    for (int j = 0; j < 4; ++j) acc[j] = db[c0 + j];
    long base = (long)(brow + r) * 128 + c0;
#pragma unroll
    for (int kc = 0; kc < 8; ++kc) {
        float4 v0 = *(const float4*)(pws + (long)kc * 262144 + base);
        acc[0] += v0.x; acc[1] += v0.y; acc[2] += v0.z; acc[3] += v0.w;
    }
    half4v hv;
#pragma unroll
    for (int j = 0; j < 4; ++j) {
        float val = fmaxf(acc[j], 0.f);
        fsm[r][c0 + j] = val;
        hv[j] = (_Float16)val;
    }
    *(half4v*)(featsH + base) = hv;
    __syncthreads();

    {
        int h = tid & 63, bg = tid >> 6;
        float a[2];
#pragma unroll
        for (int i = 0; i < 2; ++i) a[i] = rb1[h];
        for (int d = 0; d < 128; ++d) {
            float wgt = rW1[d * 64 + h];
#pragma unroll
            for (int i = 0; i < 2; ++i) a[i] += fsm[bg * 2 + i][d] * wgt;
        }
#pragma unroll
        for (int i = 0; i < 2; ++i) r1s[bg * 2 + i][h] = fmaxf(a[i], 0.f);
    }
    __syncthreads();

    if (tid < 128) {
        int b = tid >> 4, e = tid & 15;
        float a = rb2[e];
#pragma unroll 8
        for (int k = 0; k < 64; ++k) a += r1s[b][k] * rW2[k * 16 + e];
        float mx = a;
#pragma unroll
        for (int off = 1; off < 16; off <<= 1)
            mx = fmaxf(mx, __shfl_xor(mx, off, 16));
        float ex = __expf(a - mx);
        float s = ex;
#pragma unroll
        for (int off = 1; off < 16; off <<= 1)
            s += __shfl_xor(s, off, 16);
        probs[(long)(brow + b) * 16 + e] = ex / s;
    }
}

// ---------------------------------------------------------------------------
// Kernel 5: fused expert chain, f16 MFMA — 8-wave blocks. (unchanged r13)
// ---------------------------------------------------------------------------
__global__ __launch_bounds__(512) void k_expert_mfma(
    const _Float16* __restrict__ featsH,
    const _Float16* __restrict__ eW1t, const float* __restrict__ eb1,
    const float* __restrict__ g,  const float* __restrict__ bb,
    const float* __restrict__ m,  const float* __restrict__ v,
    const _Float16* __restrict__ eW2t, const float* __restrict__ eb2,
    const _Float16* __restrict__ eW3p, const float* __restrict__ eb3,
    float* __restrict__ e3p)
{
    __shared__ __align__(16) _Float16 fsH[64][136];
    __shared__ __align__(16) _Float16 h1sH[64][136];
    __shared__ __align__(16) _Float16 h2sH[64][72];
    int e = blockIdx.x, bt = blockIdx.y;
    int tid = threadIdx.x;
    int w = tid >> 6, l = tid & 63, l15 = l & 15, lq = l >> 4;
    int brow = bt * 64;
    int m0 = (w & 3) * 16;
    int nh = w >> 2;

#pragma unroll
    for (int it = 0; it < 2; ++it) {
        int idx = it * 512 + tid;
        int r = idx >> 4, c = (idx & 15) * 8;
        *(half8*)&fsH[r][c] = *(const half8*)(featsH + (long)(brow + r) * 128 + c);
    }
    __syncthreads();

    {
        half8 af[4];
#pragma unroll
        for (int kq = 0; kq < 4; ++kq)
            af[kq] = *(const half8*)&fsH[m0 + l15][kq * 32 + lq * 8];
        const _Float16* B1 = eW1t + (long)e * 16384 + (long)nh * 8192 + l15 * 128 + lq * 8;
        f32x4 acc[4];
#pragma unroll
        for (int nf = 0; nf < 4; ++nf) {
            float bv = eb1[e * 128 + nh * 64 + nf * 16 + l15];
            acc[nf] = (f32x4){ bv, bv, bv, bv };
        }
#pragma unroll
        for (int nf = 0; nf < 4; ++nf)
#pragma unroll
            for (int kq = 0; kq < 4; ++kq) {
                half8 bfv = *(const half8*)(B1 + nf * 2048 + kq * 32);
                acc[nf] = __builtin_amdgcn_mfma_f32_16x16x32_f16(af[kq], bfv, acc[nf], 0, 0, 0);
            }
#pragma unroll
        for (int nf = 0; nf < 4; ++nf) {
            int h = nh * 64 + nf * 16 + l15;
            float gg = g[e * 128 + h], bbv = bb[e * 128 + h], mm = m[e * 128 + h];
            float iv = rsqrtf(v[e * 128 + h] + EPS);
#pragma unroll
            for (int reg = 0; reg < 4; ++reg) {
                float val = fmaxf(acc[nf][reg], 0.f);
                h1sH[m0 + lq * 4 + reg][h] = (_Float16)((val - mm) * iv * gg + bbv);
            }
        }
    }
    __syncthreads();

    {
        half8 af[4];
#pragma unroll
        for (int kq = 0; kq < 4; ++kq)
            af[kq] = *(const half8*)&h1sH[m0 + l15][kq * 32 + lq * 8];
        const _Float16* B2 = eW2t + (long)e * 8192 + (long)nh * 4096 + l15 * 128 + lq * 8;
        f32x4 acc[2];
#pragma unroll
        for (int nf = 0; nf < 2; ++nf) {
            float bv = eb2[e * 64 + nh * 32 + nf * 16 + l15];
            acc[nf] = (f32x4){ bv, bv, bv, bv };
        }
#pragma unroll
        for (int nf = 0; nf < 2; ++nf)
#pragma unroll
            for (int kq = 0; kq < 4; ++kq) {
                half8 bfv = *(const half8*)(B2 + nf * 2048 + kq * 32);
                acc[nf] = __builtin_amdgcn_mfma_f32_16x16x32_f16(af[kq], bfv, acc[nf], 0, 0, 0);
            }
#pragma unroll
        for (int nf = 0; nf < 2; ++nf)
#pragma unroll
            for (int reg = 0; reg < 4; ++reg)
                h2sH[m0 + lq * 4 + reg][nh * 32 + nf * 16 + l15] =
                    (_Float16)fmaxf(acc[nf][reg], 0.f);
    }
    __syncthreads();

    if (nh == 0) {
        half8 af[2];
#pragma unroll
        for (int kq = 0; kq < 2; ++kq)
            af[kq] = *(const half8*)&h2sH[m0 + l15][kq * 32 + lq * 8];
        const _Float16* B3 = eW3p + (long)e * 1024 + l15 * 64 + lq * 8;
        float bv = (l15 < 10) ? eb3[e * 10 + l15] : 0.f;
        f32x4 acc = (f32x4){ bv, bv, bv, bv };
#pragma unroll
        for (int kq = 0; kq < 2; ++kq) {
            half8 bfv = *(const half8*)(B3 + kq * 32);
            acc = __builtin_amdgcn_mfma_f32_16x16x32_f16(af[kq], bfv, acc, 0, 0, 0);
        }
#pragma unroll
        for (int reg = 0; reg < 4; ++reg) {
            int b = brow + m0 + lq * 4 + reg;
            e3p[((long)e * 2048 + b) * 16 + l15] = acc[reg];
        }
    }
}

// ---------------------------------------------------------------------------
// Kernel 6: combine.
// ---------------------------------------------------------------------------
__global__ __launch_bounds__(256) void k_combine(
    const float* __restrict__ e3p, const float* __restrict__ probs,
    float* __restrict__ out)
{
    int t = blockIdx.x * blockDim.x + threadIdx.x;
    if (t >= 2048 * 10) return;
    int b = t / 10, c = t % 10;
    float acc = 0.f;
#pragma unroll
    for (int e = 0; e < 16; ++e)
        acc += probs[(long)b * 16 + e] * e3p[((long)e * 2048 + b) * 16 + c];
    out[t] = acc;
}

// ---------------------------------------------------------------------------
extern "C" void kernel_launch(void* const* d_in, const int* in_sizes, int n_in,
                              void* d_out, int out_size, void* d_ws, size_t ws_size,
                              hipStream_t stream)
{
    const float* x    = (const float*)d_in[0];
    const float* cW1  = (const float*)d_in[1];
    const float* cb1  = (const float*)d_in[2];
    const float* bn1g = (const float*)d_in[3];
    const float* bn1b = (const float*)d_in[4];
    const float* bn1m = (const float*)d_in[5];
    const float* bn1v = (const float*)d_in[6];
    const float* cW2  = (const float*)d_in[7];
    const float* cb2  = (const float*)d_in[8];
    const float* bn2g = (const float*)d_in[9];
    const float* bn2b = (const float*)d_in[10];
    const float* bn2m = (const float*)d_in[11];
    const float* bn2v = (const float*)d_in[12];
    const float* dW   = (const float*)d_in[13];
    const float* db   = (const float*)d_in[14];
    const float* rW1  = (const float*)d_in[15];
    const float* rb1  = (const float*)d_in[16];
    const float* rW2  = (const float*)d_in[17];
    const float* rb2  = (const float*)d_in[18];
    const float* eW1  = (const float*)d_in[19];
    const float* eb1  = (const float*)d_in[20];
    const float* ebng = (const float*)d_in[21];
    const float* ebnb = (const float*)d_in[22];
    const float* ebnm = (const float*)d_in[23];
    const float* ebnv = (const float*)d_in[24];
    const float* eW2  = (const float*)d_in[25];
    const float* eb2  = (const float*)d_in[26];
    const float* eW3  = (const float*)d_in[27];
    const float* eb3  = (const float*)d_in[28];

    float* ws    = (float*)d_ws;
    float* h1reg = ws;
    float* e3p   = h1reg;                                  // [0 .. 524,288) floats
    _Float16* featsH = (_Float16*)(h1reg + 524288);        // 262,144 f16
    float* h2reg = h1reg + 16777216;
    _Float16* h2f = (_Float16*)h2reg;                      // conv2 out f16 [2048][4096]
    _Float16* Wt2 = (_Float16*)(h2reg + 4194304);          // dense weights f16 [128][4096]
    float* probs = h2reg + 8388608;
    float* ewreg = probs + 32768;
    _Float16* eW1t = (_Float16*)ewreg;
    _Float16* eW2t = eW1t + 262144;
    _Float16* eW3p = eW2t + 131072;
    _Float16* Wt   = eW3p + 16384;
    _Float16* Wt1  = Wt + 18432;
    float* pws   = ewreg + 262144;
    float* out   = (float*)d_out;

    k_wprep_all<<<244, 256, 0, stream>>>(dW, Wt2, eW1, eW1t, eW2, eW2t,
                                         cW1, Wt1, cW2, Wt, eW3, eW3p);
    {
        dim3 grid(2048, 2);
        k_conv12<<<grid, 256, 0, stream>>>(x, Wt1, cb1, bn1g, bn1b, bn1m, bn1v,
                                           Wt, cb2, bn2g, bn2b, bn2m, bn2v, h2f);
    }
    {
        dim3 grid(128, 8);
        k_dense_mfma<<<grid, 256, 0, stream>>>(h2f, Wt2, pws);
    }
    k_reduce_router<<<256, 256, 0, stream>>>(pws, db, rW1, rb1, rW2, rb2,
                                             featsH, probs);
    {
        dim3 grid(16, 32);
        k_expert_mfma<<<grid, 512, 0, stream>>>(featsH, eW1t, eb1, ebng, ebnb, ebnm, ebnv,
                                                eW2t, eb2, eW3p, eb3, e3p);
    }
    k_combine<<<80, 256, 0, stream>>>(e3p, probs, out);
}

// Round 15
// 92.693 us; speedup vs baseline: 1.1656x; 1.1656x over previous
//
#include <hip/hip_runtime.h>

#define EPS 1e-3f

typedef _Float16 half8 __attribute__((ext_vector_type(8)));
typedef _Float16 half4v __attribute__((ext_vector_type(4)));
typedef float f32x4 __attribute__((ext_vector_type(4)));

// ---------------------------------------------------------------------------
// Merged weight prep (single dispatch), branch by block range:
//  blocks [0,64):   dW fp32 [4096][128] -> Wt2 f16 [128][4096]        (LDS transpose)
//  blocks [64,80):  eW1 [16][128d][128h] -> eW1t f16 [16][128h][128d] (LDS transpose)
//  blocks [80,96):  eW2 [16][128h][64k]  -> eW2t f16 [16][64k][128h]  (LDS transpose)
//  blocks [96,244): cW1 -> Wt1 [2pair][32co][32k]  k=kyin*16+kxp*4+ci, ky=2p+kyin
//                   cW2 -> Wt  [9tap][64co][32ci]
//                   eW3 -> eW3p [16][16n(pad0)][64k]
// ---------------------------------------------------------------------------
__global__ __launch_bounds__(256) void k_wprep_all(
    const float* __restrict__ dW,  _Float16* __restrict__ Wt2,
    const float* __restrict__ eW1, _Float16* __restrict__ eW1t,
    const float* __restrict__ eW2, _Float16* __restrict__ eW2t,
    const float* __restrict__ cW1, _Float16* __restrict__ Wt1,
    const float* __restrict__ cW2, _Float16* __restrict__ Wt,
    const float* __restrict__ eW3, _Float16* __restrict__ eW3p)
{
    __shared__ _Float16 lsbuf[16640];
    int bx = blockIdx.x, tid = threadIdx.x;

    if (bx < 64) {
        auto lt = (_Float16(*)[137])lsbuf;       // [64][137]
        int kb = bx * 64;
        int c = tid & 127, r2 = tid >> 7;
#pragma unroll
        for (int it = 0; it < 32; ++it) {
            int r = it * 2 + r2;
            lt[r][c] = (_Float16)dW[(long)(kb + r) * 128 + c];
        }
        __syncthreads();
#pragma unroll
        for (int it = 0; it < 4; ++it) {
            int chunk = it * 256 + tid;
            int n = chunk >> 3, kc = (chunk & 7) * 8;
            half8 v;
#pragma unroll
            for (int j = 0; j < 8; ++j) v[j] = lt[kc + j][n];
            *(half8*)(Wt2 + (long)n * 4096 + kb + kc) = v;
        }
    } else if (bx < 80) {
        auto lt = (_Float16(*)[130])lsbuf;       // [128][130]
        int e = bx - 64;
        const float* src = eW1 + (long)e * 16384;
#pragma unroll
        for (int it = 0; it < 64; ++it) {
            int idx = it * 256 + tid;
            lt[idx >> 7][idx & 127] = (_Float16)src[idx];
        }
        __syncthreads();
        _Float16* dst = eW1t + (long)e * 16384;
#pragma unroll
        for (int it = 0; it < 64; ++it) {
            int idx = it * 256 + tid;            // idx = h*128 + d
            dst[idx] = lt[idx & 127][idx >> 7];
        }
    } else if (bx < 96) {
        auto lt = (_Float16(*)[66])lsbuf;        // [128][66]
        int e = bx - 80;
        const float* src = eW2 + (long)e * 8192;
#pragma unroll
        for (int it = 0; it < 32; ++it) {
            int idx = it * 256 + tid;
            lt[idx >> 6][idx & 63] = (_Float16)src[idx];
        }
        __syncthreads();
        _Float16* dst = eW2t + (long)e * 8192;
#pragma unroll
        for (int it = 0; it < 32; ++it) {
            int idx = it * 256 + tid;            // idx = n*128 + d
            dst[idx] = lt[idx & 127][idx >> 7];
        }
    } else {
        int t = (bx - 96) * 256 + tid;
        if (t < 2048) {
            int k = t & 31, co = (t >> 5) & 31, p = t >> 10;
            int kyin = (k >> 4) & 1, kxp = (k >> 2) & 3, ci = k & 3;
            int ky = 2 * p + kyin;
            float val = (ky < 3 && kxp < 3 && ci < 3)
                        ? cW1[((ky * 3 + kxp) * 3 + ci) * 32 + co] : 0.f;
            Wt1[t] = (_Float16)val;
        } else if (t >= 3072 && t < 3072 + 18432) {
            int u = t - 3072;
            int co = u & 63;
            int rest = u >> 6;
            int ci = rest & 31, tap = rest >> 5;
            Wt[(tap * 64 + co) * 32 + ci] = (_Float16)cW2[u];
        } else if (t >= 21504 && t < 21504 + 16384) {
            int u = t - 21504;
            int k = u & 63, n = (u >> 6) & 15, e = u >> 10;
            float val = (n < 10) ? eW3[(e * 64 + k) * 10 + n] : 0.f;
            eW3p[(e * 16 + n) * 64 + k] = (_Float16)val;
        }
    }
}

// ---------------------------------------------------------------------------
// Fused conv1+conv2, f16 MFMA, one block per image. (r12 proven version:
// whole image, ky-paired Phase A, per-tap B-frag loads, S/T-form BN.)
// r14's half-image split regressed (per-block overhead dominates); reverted.
// ---------------------------------------------------------------------------
__global__ __launch_bounds__(256) void k_conv12(
    const float* __restrict__ x, const _Float16* __restrict__ Wt1,
    const float* __restrict__ b1, const float* __restrict__ g1,
    const float* __restrict__ bb1, const float* __restrict__ m1,
    const float* __restrict__ v1,
    const _Float16* __restrict__ Wt,
    const float* __restrict__ b2, const float* __restrict__ g2,
    const float* __restrict__ bb2, const float* __restrict__ m2,
    const float* __restrict__ v2,
    _Float16* __restrict__ out)
{
    __shared__ __align__(16) _Float16 As1[35][40][4];   // 700 float4
    __shared__ __align__(16) _Float16 As2[18][18][40];  // 1620 float4
    int tid = threadIdx.x;
    int b = blockIdx.x;
    int w = tid >> 6, l = tid & 63;
    int l15 = l & 15, lq = l >> 4;
    int lqr = lq >> 1, lqc = (lq & 1) * 2;

    {
        float4 z = make_float4(0.f, 0.f, 0.f, 0.f);
        float4* f1p = (float4*)&As1[0][0][0];
        for (int i = tid; i < 700; i += 256) f1p[i] = z;
        float4* f2p = (float4*)&As2[0][0][0];
        for (int i = tid; i < 1620; i += 256) f2p[i] = z;
    }
    __syncthreads();

    {
        int y = tid >> 3, x0 = (tid & 7) * 4;
        const float* src = x + ((long)b * 1024 + y * 32 + x0) * 3;
        float4 f0 = *(const float4*)(src);
        float4 f1 = *(const float4*)(src + 4);
        float4 f2 = *(const float4*)(src + 8);
        half4v h0 = { (_Float16)f0.x, (_Float16)f0.y, (_Float16)f0.z, (_Float16)0.f };
        half4v h1 = { (_Float16)f0.w, (_Float16)f1.x, (_Float16)f1.y, (_Float16)0.f };
        half4v h2 = { (_Float16)f1.z, (_Float16)f1.w, (_Float16)f2.x, (_Float16)0.f };
        half4v h3 = { (_Float16)f2.y, (_Float16)f2.z, (_Float16)f2.w, (_Float16)0.f };
        *(half4v*)&As1[y + 1][x0 + 1][0] = h0;
        *(half4v*)&As1[y + 1][x0 + 2][0] = h1;
        *(half4v*)&As1[y + 1][x0 + 3][0] = h2;
        *(half4v*)&As1[y + 1][x0 + 4][0] = h3;
    }

    half8 bf1[2][2];
#pragma unroll
    for (int p = 0; p < 2; ++p)
#pragma unroll
        for (int nf = 0; nf < 2; ++nf)
            bf1[p][nf] = *(const half8*)(Wt1 + (p * 32 + nf * 16 + l15) * 32 + lq * 8);

    float bv1[2], S1[2], T1[2];
#pragma unroll
    for (int nf = 0; nf < 2; ++nf) {
        int co = nf * 16 + l15;
        bv1[nf] = b1[co];
        float s = rsqrtf(v1[co] + EPS) * g1[co];
        S1[nf] = s;
        T1[nf] = bb1[co] - m1[co] * s;
    }
    __syncthreads();

    {
        int y0 = w * 8;
#pragma unroll
        for (int pr = 0; pr < 4; ++pr) {
            int ya = y0 + 2 * pr;
            f32x4 acc[2][2][2];
#pragma unroll
            for (int r = 0; r < 2; ++r)
#pragma unroll
                for (int h = 0; h < 2; ++h)
#pragma unroll
                    for (int nf = 0; nf < 2; ++nf)
                        acc[r][h][nf] = (f32x4){ bv1[nf], bv1[nf], bv1[nf], bv1[nf] };

#pragma unroll
            for (int p = 0; p < 2; ++p)
#pragma unroll
                for (int r = 0; r < 2; ++r)
#pragma unroll
                    for (int h = 0; h < 2; ++h) {
                        const _Float16* ap = &As1[ya + r + 2 * p + lqr][h * 16 + l15 + lqc][0];
                        half4v a0 = *(const half4v*)ap;
                        half4v a1 = *(const half4v*)(ap + 4);
                        half8 af = __builtin_shufflevector(a0, a1, 0, 1, 2, 3, 4, 5, 6, 7);
#pragma unroll
                        for (int nf = 0; nf < 2; ++nf)
                            acc[r][h][nf] = __builtin_amdgcn_mfma_f32_16x16x32_f16(
                                af, bf1[p][nf], acc[r][h][nf], 0, 0, 0);
                    }

            int py = w * 4 + pr;
#pragma unroll
            for (int h = 0; h < 2; ++h)
#pragma unroll
                for (int nf = 0; nf < 2; ++nf) {
                    f32x4 aA = acc[0][h][nf], aB = acc[1][h][nf];
                    float p0 = fmaxf(fmaxf(aA[0], aA[1]), fmaxf(aB[0], aB[1]));
                    float p1 = fmaxf(fmaxf(aA[2], aA[3]), fmaxf(aB[2], aB[3]));
                    p0 = fmaxf(p0, 0.f); p1 = fmaxf(p1, 0.f);
                    p0 = fmaf(p0, S1[nf], T1[nf]);
                    p1 = fmaf(p1, S1[nf], T1[nf]);
                    int px = h * 8 + lq * 2;
                    int co = nf * 16 + l15;
                    As2[py + 1][px + 1][co] = (_Float16)p0;
                    As2[py + 1][px + 2][co] = (_Float16)p1;
                }
        }
    }
    __syncthreads();

    f32x4 acc2[4][4];
#pragma unroll
    for (int nf = 0; nf < 4; ++nf) {
        float bv = b2[nf * 16 + l15];
#pragma unroll
        for (int mf = 0; mf < 4; ++mf)
            acc2[mf][nf] = (f32x4){ bv, bv, bv, bv };
    }

    int row0 = 4 * w;
#pragma unroll
    for (int tap = 0; tap < 9; ++tap) {
        int ky = tap / 3, kx = tap % 3;
        half8 bf[4];
        const _Float16* wb = Wt + ((long)(tap * 64 + l15)) * 32 + lq * 8;
#pragma unroll
        for (int nf = 0; nf < 4; ++nf)
            bf[nf] = *(const half8*)(wb + (long)nf * 16 * 32);
#pragma unroll
        for (int mf = 0; mf < 4; ++mf) {
            const _Float16* ap = &As2[row0 + mf + ky][l15 + kx][lq * 8];
            half8 af = *(const half8*)ap;
#pragma unroll
            for (int nf = 0; nf < 4; ++nf)
                acc2[mf][nf] = __builtin_amdgcn_mfma_f32_16x16x32_f16(
                    af, bf[nf], acc2[mf][nf], 0, 0, 0);
        }
    }

#pragma unroll
    for (int nf = 0; nf < 4; ++nf) {
        int co = nf * 16 + l15;
        float s = rsqrtf(v2[co] + EPS) * g2[co];
        float t2 = bb2[co] - m2[co] * s;
#pragma unroll
        for (int pr = 0; pr < 2; ++pr) {
            int prow = 2 * w + pr;
            f32x4 a0 = acc2[2 * pr][nf];
            f32x4 a1 = acc2[2 * pr + 1][nf];
            float p0 = fmaxf(fmaxf(a0[0], a0[1]), fmaxf(a1[0], a1[1]));
            float p1 = fmaxf(fmaxf(a0[2], a0[3]), fmaxf(a1[2], a1[3]));
            p0 = fmaxf(p0, 0.f);
            p1 = fmaxf(p1, 0.f);
            int ppx = lq * 2;
            long base = (((long)b * 8 + prow) * 8) * 64 + co;
            out[base + (long)(ppx    ) * 64] = (_Float16)fmaf(p0, s, t2);
            out[base + (long)(ppx + 1) * 64] = (_Float16)fmaf(p1, s, t2);
        }
    }
}

// ---------------------------------------------------------------------------
// Kernel 3a: dense 4096 -> 128, split-K x8, f16 MFMA. (unchanged)
// ---------------------------------------------------------------------------
__global__ __launch_bounds__(256) void k_dense_mfma(
    const _Float16* __restrict__ h2f, const _Float16* __restrict__ Wt2,
    float* __restrict__ pws)
{
    __shared__ __align__(16) _Float16 As[16][264];
    int tid = threadIdx.x;
    int w = tid >> 6, l = tid & 63;
    int l15 = l & 15, lq = l >> 4;
    int brow = blockIdx.x * 16;
    int kbase = blockIdx.y * 512;
    int n0 = w * 32;

    f32x4 acc[2] = { (f32x4){0.f,0.f,0.f,0.f}, (f32x4){0.f,0.f,0.f,0.f} };

    int srow = tid >> 4, sc = (tid & 15) * 16;
#pragma unroll
    for (int k0 = 0; k0 < 512; k0 += 256) {
        __syncthreads();
        const _Float16* src = h2f + (long)(brow + srow) * 4096 + kbase + k0 + sc;
        half8 v0 = *(const half8*)src;
        half8 v1 = *(const half8*)(src + 8);
        *(half8*)(&As[srow][sc])     = v0;
        *(half8*)(&As[srow][sc + 8]) = v1;
        __syncthreads();
#pragma unroll
        for (int kk = 0; kk < 256; kk += 32) {
            half8 af = *(const half8*)(&As[l15][kk + lq * 8]);
#pragma unroll
            for (int nf = 0; nf < 2; ++nf) {
                half8 bf = *(const half8*)(Wt2 + (long)(n0 + nf * 16 + l15) * 4096
                                           + kbase + k0 + kk + lq * 8);
                acc[nf] = __builtin_amdgcn_mfma_f32_16x16x32_f16(af, bf, acc[nf], 0, 0, 0);
            }
        }
    }

    float* pbase = pws + (long)blockIdx.y * 262144;
#pragma unroll
    for (int nf = 0; nf < 2; ++nf) {
        int n = n0 + nf * 16 + l15;
#pragma unroll
        for (int reg = 0; reg < 4; ++reg) {
            int b = brow + lq * 4 + reg;
            pbase[(long)b * 128 + n] = acc[nf][reg];
        }
    }
}

// ---------------------------------------------------------------------------
// Kernel 3b: fused split-K reduce + bias + relu -> featsH, then router MLP
// + softmax. One block per 8 batch rows (grid 256). (unchanged r13)
// ---------------------------------------------------------------------------
__global__ __launch_bounds__(256) void k_reduce_router(
    const float* __restrict__ pws, const float* __restrict__ db,
    const float* __restrict__ rW1, const float* __restrict__ rb1,
    const float* __restrict__ rW2, const float* __restrict__ rb2,
    _Float16* __restrict__ featsH, float* __restrict__ probs)
{
    __shared__ float fsm[8][128];
    __shared__ float r1s[8][64];
    int tid = threadIdx.x;
    int brow = blockIdx.x * 8;
    int r = tid >> 5, c0 = (tid & 31) * 4;

    float acc[4];
#pragma unroll
    for (int j = 0; j < 4; ++j) acc[j] = db[c0 + j];
    long base = (long)(brow + r) * 128 + c0;
#pragma unroll
    for (int kc = 0; kc < 8; ++kc) {
        float4 v0 = *(const float4*)(pws + (long)kc * 262144 + base);
        acc[0] += v0.x; acc[1] += v0.y; acc[2] += v0.z; acc[3] += v0.w;
    }
    half4v hv;
#pragma unroll
    for (int j = 0; j < 4; ++j) {
        float val = fmaxf(acc[j], 0.f);
        fsm[r][c0 + j] = val;
        hv[j] = (_Float16)val;
    }
    *(half4v*)(featsH + base) = hv;
    __syncthreads();

    {
        int h = tid & 63, bg = tid >> 6;
        float a[2];
#pragma unroll
        for (int i = 0; i < 2; ++i) a[i] = rb1[h];
        for (int d = 0; d < 128; ++d) {
            float wgt = rW1[d * 64 + h];
#pragma unroll
            for (int i = 0; i < 2; ++i) a[i] += fsm[bg * 2 + i][d] * wgt;
        }
#pragma unroll
        for (int i = 0; i < 2; ++i) r1s[bg * 2 + i][h] = fmaxf(a[i], 0.f);
    }
    __syncthreads();

    if (tid < 128) {
        int b = tid >> 4, e = tid & 15;
        float a = rb2[e];
#pragma unroll 8
        for (int k = 0; k < 64; ++k) a += r1s[b][k] * rW2[k * 16 + e];
        float mx = a;
#pragma unroll
        for (int off = 1; off < 16; off <<= 1)
            mx = fmaxf(mx, __shfl_xor(mx, off, 16));
        float ex = __expf(a - mx);
        float s = ex;
#pragma unroll
        for (int off = 1; off < 16; off <<= 1)
            s += __shfl_xor(s, off, 16);
        probs[(long)(brow + b) * 16 + e] = ex / s;
    }
}

// ---------------------------------------------------------------------------
// Kernel 5: fused expert chain, f16 MFMA — 8-wave blocks, COMBINE FUSED:
// phase 3 multiplies by probs[b][e] and atomicAdds into out[b][c] (out
// pre-zeroed via hipMemsetAsync). Eliminates e3p buffer + k_combine launch.
// ---------------------------------------------------------------------------
__global__ __launch_bounds__(512) void k_expert_mfma(
    const _Float16* __restrict__ featsH,
    const _Float16* __restrict__ eW1t, const float* __restrict__ eb1,
    const float* __restrict__ g,  const float* __restrict__ bb,
    const float* __restrict__ m,  const float* __restrict__ v,
    const _Float16* __restrict__ eW2t, const float* __restrict__ eb2,
    const _Float16* __restrict__ eW3p, const float* __restrict__ eb3,
    const float* __restrict__ probs, float* __restrict__ outp)
{
    __shared__ __align__(16) _Float16 fsH[64][136];
    __shared__ __align__(16) _Float16 h1sH[64][136];
    __shared__ __align__(16) _Float16 h2sH[64][72];
    int e = blockIdx.x, bt = blockIdx.y;
    int tid = threadIdx.x;
    int w = tid >> 6, l = tid & 63, l15 = l & 15, lq = l >> 4;
    int brow = bt * 64;
    int m0 = (w & 3) * 16;
    int nh = w >> 2;

#pragma unroll
    for (int it = 0; it < 2; ++it) {
        int idx = it * 512 + tid;
        int r = idx >> 4, c = (idx & 15) * 8;
        *(half8*)&fsH[r][c] = *(const half8*)(featsH + (long)(brow + r) * 128 + c);
    }
    __syncthreads();

    // phase 1: [64x128] @ [128x128] + BN + relu
    {
        half8 af[4];
#pragma unroll
        for (int kq = 0; kq < 4; ++kq)
            af[kq] = *(const half8*)&fsH[m0 + l15][kq * 32 + lq * 8];
        const _Float16* B1 = eW1t + (long)e * 16384 + (long)nh * 8192 + l15 * 128 + lq * 8;
        f32x4 acc[4];
#pragma unroll
        for (int nf = 0; nf < 4; ++nf) {
            float bv = eb1[e * 128 + nh * 64 + nf * 16 + l15];
            acc[nf] = (f32x4){ bv, bv, bv, bv };
        }
#pragma unroll
        for (int nf = 0; nf < 4; ++nf)
#pragma unroll
            for (int kq = 0; kq < 4; ++kq) {
                half8 bfv = *(const half8*)(B1 + nf * 2048 + kq * 32);
                acc[nf] = __builtin_amdgcn_mfma_f32_16x16x32_f16(af[kq], bfv, acc[nf], 0, 0, 0);
            }
#pragma unroll
        for (int nf = 0; nf < 4; ++nf) {
            int h = nh * 64 + nf * 16 + l15;
            float gg = g[e * 128 + h], bbv = bb[e * 128 + h], mm = m[e * 128 + h];
            float iv = rsqrtf(v[e * 128 + h] + EPS);
#pragma unroll
            for (int reg = 0; reg < 4; ++reg) {
                float val = fmaxf(acc[nf][reg], 0.f);
                h1sH[m0 + lq * 4 + reg][h] = (_Float16)((val - mm) * iv * gg + bbv);
            }
        }
    }
    __syncthreads();

    // phase 2: [64x128] @ [128x64] + relu
    {
        half8 af[4];
#pragma unroll
        for (int kq = 0; kq < 4; ++kq)
            af[kq] = *(const half8*)&h1sH[m0 + l15][kq * 32 + lq * 8];
        const _Float16* B2 = eW2t + (long)e * 8192 + (long)nh * 4096 + l15 * 128 + lq * 8;
        f32x4 acc[2];
#pragma unroll
        for (int nf = 0; nf < 2; ++nf) {
            float bv = eb2[e * 64 + nh * 32 + nf * 16 + l15];
            acc[nf] = (f32x4){ bv, bv, bv, bv };
        }
#pragma unroll
        for (int nf = 0; nf < 2; ++nf)
#pragma unroll
            for (int kq = 0; kq < 4; ++kq) {
                half8 bfv = *(const half8*)(B2 + nf * 2048 + kq * 32);
                acc[nf] = __builtin_amdgcn_mfma_f32_16x16x32_f16(af[kq], bfv, acc[nf], 0, 0, 0);
            }
#pragma unroll
        for (int nf = 0; nf < 2; ++nf)
#pragma unroll
            for (int reg = 0; reg < 4; ++reg)
                h2sH[m0 + lq * 4 + reg][nh * 32 + nf * 16 + l15] =
                    (_Float16)fmaxf(acc[nf][reg], 0.f);
    }
    __syncthreads();

    // phase 3: [64x64] @ [64x16(pad)] -> probs-weighted atomicAdd into out
    if (nh == 0) {
        half8 af[2];
#pragma unroll
        for (int kq = 0; kq < 2; ++kq)
            af[kq] = *(const half8*)&h2sH[m0 + l15][kq * 32 + lq * 8];
        const _Float16* B3 = eW3p + (long)e * 1024 + l15 * 64 + lq * 8;
        float bv = (l15 < 10) ? eb3[e * 10 + l15] : 0.f;
        f32x4 acc = (f32x4){ bv, bv, bv, bv };
#pragma unroll
        for (int kq = 0; kq < 2; ++kq) {
            half8 bfv = *(const half8*)(B3 + kq * 32);
            acc = __builtin_amdgcn_mfma_f32_16x16x32_f16(af[kq], bfv, acc, 0, 0, 0);
        }
        if (l15 < 10) {
#pragma unroll
            for (int reg = 0; reg < 4; ++reg) {
                int b = brow + m0 + lq * 4 + reg;
                float p = probs[(long)b * 16 + e];
                atomicAdd(&outp[(long)b * 10 + l15], p * acc[reg]);
            }
        }
    }
}

// ---------------------------------------------------------------------------
extern "C" void kernel_launch(void* const* d_in, const int* in_sizes, int n_in,
                              void* d_out, int out_size, void* d_ws, size_t ws_size,
                              hipStream_t stream)
{
    const float* x    = (const float*)d_in[0];
    const float* cW1  = (const float*)d_in[1];
    const float* cb1  = (const float*)d_in[2];
    const float* bn1g = (const float*)d_in[3];
    const float* bn1b = (const float*)d_in[4];
    const float* bn1m = (const float*)d_in[5];
    const float* bn1v = (const float*)d_in[6];
    const float* cW2  = (const float*)d_in[7];
    const float* cb2  = (const float*)d_in[8];
    const float* bn2g = (const float*)d_in[9];
    const float* bn2b = (const float*)d_in[10];
    const float* bn2m = (const float*)d_in[11];
    const float* bn2v = (const float*)d_in[12];
    const float* dW   = (const float*)d_in[13];
    const float* db   = (const float*)d_in[14];
    const float* rW1  = (const float*)d_in[15];
    const float* rb1  = (const float*)d_in[16];
    const float* rW2  = (const float*)d_in[17];
    const float* rb2  = (const float*)d_in[18];
    const float* eW1  = (const float*)d_in[19];
    const float* eb1  = (const float*)d_in[20];
    const float* ebng = (const float*)d_in[21];
    const float* ebnb = (const float*)d_in[22];
    const float* ebnm = (const float*)d_in[23];
    const float* ebnv = (const float*)d_in[24];
    const float* eW2  = (const float*)d_in[25];
    const float* eb2  = (const float*)d_in[26];
    const float* eW3  = (const float*)d_in[27];
    const float* eb3  = (const float*)d_in[28];

    float* ws    = (float*)d_ws;
    // --- region 1 (recycled): featsH ---
    float* h1reg = ws;
    _Float16* featsH = (_Float16*)(h1reg + 524288);        // 262,144 f16
    // --- region 2: h2reg ---
    float* h2reg = h1reg + 16777216;
    _Float16* h2f = (_Float16*)h2reg;                      // conv2 out f16 [2048][4096]
    _Float16* Wt2 = (_Float16*)(h2reg + 4194304);          // dense weights f16 [128][4096]
    // --- region 3: small tensors ---
    float* probs = h2reg + 8388608;
    float* ewreg = probs + 32768;
    _Float16* eW1t = (_Float16*)ewreg;             // 262,144 f16
    _Float16* eW2t = eW1t + 262144;                // 131,072 f16
    _Float16* eW3p = eW2t + 131072;                //  16,384 f16
    _Float16* Wt   = eW3p + 16384;                 //  18,432 f16 (conv2 w)
    _Float16* Wt1  = Wt + 18432;                   //   3,072 f16 slot (conv1 w)
    // --- region 4: dense split-K partials [8][2048][128] fp32 ---
    float* pws   = ewreg + 262144;
    float* outp  = (float*)d_out;

    // out must be zero for the expert kernel's atomic accumulation
    hipMemsetAsync(d_out, 0, (size_t)out_size * sizeof(float), stream);

    k_wprep_all<<<244, 256, 0, stream>>>(dW, Wt2, eW1, eW1t, eW2, eW2t,
                                         cW1, Wt1, cW2, Wt, eW3, eW3p);
    k_conv12<<<2048, 256, 0, stream>>>(x, Wt1, cb1, bn1g, bn1b, bn1m, bn1v,
                                       Wt, cb2, bn2g, bn2b, bn2m, bn2v, h2f);
    {
        dim3 grid(128, 8);
        k_dense_mfma<<<grid, 256, 0, stream>>>(h2f, Wt2, pws);
    }
    k_reduce_router<<<256, 256, 0, stream>>>(pws, db, rW1, rb1, rW2, rb2,
                                             featsH, probs);
    {
        dim3 grid(16, 32);
        k_expert_mfma<<<grid, 512, 0, stream>>>(featsH, eW1t, eb1, ebng, ebnb, ebnm, ebnv,
                                                eW2t, eb2, eW3p, eb3, probs, outp);
    }
}

// Round 16
// 86.535 us; speedup vs baseline: 1.2486x; 1.0712x over previous
//
#include <hip/hip_runtime.h>

#define EPS 1e-3f

typedef _Float16 half8 __attribute__((ext_vector_type(8)));
typedef _Float16 half4v __attribute__((ext_vector_type(4)));
typedef float f32x4 __attribute__((ext_vector_type(4)));

// ---------------------------------------------------------------------------
// Merged weight prep (single dispatch), branch by block range (r13).
// ---------------------------------------------------------------------------
__global__ __launch_bounds__(256) void k_wprep_all(
    const float* __restrict__ dW,  _Float16* __restrict__ Wt2,
    const float* __restrict__ eW1, _Float16* __restrict__ eW1t,
    const float* __restrict__ eW2, _Float16* __restrict__ eW2t,
    const float* __restrict__ cW1, _Float16* __restrict__ Wt1,
    const float* __restrict__ cW2, _Float16* __restrict__ Wt,
    const float* __restrict__ eW3, _Float16* __restrict__ eW3p)
{
    __shared__ _Float16 lsbuf[16640];
    int bx = blockIdx.x, tid = threadIdx.x;

    if (bx < 64) {
        auto lt = (_Float16(*)[137])lsbuf;       // [64][137]
        int kb = bx * 64;
        int c = tid & 127, r2 = tid >> 7;
#pragma unroll
        for (int it = 0; it < 32; ++it) {
            int r = it * 2 + r2;
            lt[r][c] = (_Float16)dW[(long)(kb + r) * 128 + c];
        }
        __syncthreads();
#pragma unroll
        for (int it = 0; it < 4; ++it) {
            int chunk = it * 256 + tid;
            int n = chunk >> 3, kc = (chunk & 7) * 8;
            half8 v;
#pragma unroll
            for (int j = 0; j < 8; ++j) v[j] = lt[kc + j][n];
            *(half8*)(Wt2 + (long)n * 4096 + kb + kc) = v;
        }
    } else if (bx < 80) {
        auto lt = (_Float16(*)[130])lsbuf;       // [128][130]
        int e = bx - 64;
        const float* src = eW1 + (long)e * 16384;
#pragma unroll
        for (int it = 0; it < 64; ++it) {
            int idx = it * 256 + tid;
            lt[idx >> 7][idx & 127] = (_Float16)src[idx];
        }
        __syncthreads();
        _Float16* dst = eW1t + (long)e * 16384;
#pragma unroll
        for (int it = 0; it < 64; ++it) {
            int idx = it * 256 + tid;            // idx = h*128 + d
            dst[idx] = lt[idx & 127][idx >> 7];
        }
    } else if (bx < 96) {
        auto lt = (_Float16(*)[66])lsbuf;        // [128][66]
        int e = bx - 80;
        const float* src = eW2 + (long)e * 8192;
#pragma unroll
        for (int it = 0; it < 32; ++it) {
            int idx = it * 256 + tid;
            lt[idx >> 6][idx & 63] = (_Float16)src[idx];
        }
        __syncthreads();
        _Float16* dst = eW2t + (long)e * 8192;
#pragma unroll
        for (int it = 0; it < 32; ++it) {
            int idx = it * 256 + tid;            // idx = n*128 + d
            dst[idx] = lt[idx & 127][idx >> 7];
        }
    } else {
        int t = (bx - 96) * 256 + tid;
        if (t < 2048) {
            int k = t & 31, co = (t >> 5) & 31, p = t >> 10;
            int kyin = (k >> 4) & 1, kxp = (k >> 2) & 3, ci = k & 3;
            int ky = 2 * p + kyin;
            float val = (ky < 3 && kxp < 3 && ci < 3)
                        ? cW1[((ky * 3 + kxp) * 3 + ci) * 32 + co] : 0.f;
            Wt1[t] = (_Float16)val;
        } else if (t >= 3072 && t < 3072 + 18432) {
            int u = t - 3072;
            int co = u & 63;
            int rest = u >> 6;
            int ci = rest & 31, tap = rest >> 5;
            Wt[(tap * 64 + co) * 32 + ci] = (_Float16)cW2[u];
        } else if (t >= 21504 && t < 21504 + 16384) {
            int u = t - 21504;
            int k = u & 63, n = (u >> 6) & 15, e = u >> 10;
            float val = (n < 10) ? eW3[(e * 64 + k) * 10 + n] : 0.f;
            eW3p[(e * 16 + n) * 64 + k] = (_Float16)val;
        }
    }
}

// ---------------------------------------------------------------------------
// Fused conv1+conv2, f16 MFMA, one block per image. r12/r13-proven structure;
// NEW: halo-only LDS zeroing (disjoint from staged/computed interiors) which
// also removes the first barrier. Pad ci 32..39 of As2 is never read.
// ---------------------------------------------------------------------------
__global__ __launch_bounds__(256) void k_conv12(
    const float* __restrict__ x, const _Float16* __restrict__ Wt1,
    const float* __restrict__ b1, const float* __restrict__ g1,
    const float* __restrict__ bb1, const float* __restrict__ m1,
    const float* __restrict__ v1,
    const _Float16* __restrict__ Wt,
    const float* __restrict__ b2, const float* __restrict__ g2,
    const float* __restrict__ bb2, const float* __restrict__ m2,
    const float* __restrict__ v2,
    _Float16* __restrict__ out)
{
    __shared__ __align__(16) _Float16 As1[35][40][4];   // rows 1..32 staged; halo zeroed
    __shared__ __align__(16) _Float16 As2[18][18][40];  // rows/cols 1..16 computed; halo zeroed
    int tid = threadIdx.x;
    int b = blockIdx.x;
    int w = tid >> 6, l = tid & 63;
    int l15 = l & 15, lq = l >> 4;
    int lqr = lq >> 1, lqc = (lq & 1) * 2;

    // halo-only zeroing (disjoint from interior writes -> no barrier needed
    // between this and staging; pre-Phase-A barrier covers everything).
    {
        half4v z4 = { (_Float16)0.f, (_Float16)0.f, (_Float16)0.f, (_Float16)0.f };
        // As1: rows {0,33,34} all 40 cols ; cols {0,33,34} of rows 1..32
        for (int i = tid; i < 216; i += 256) {
            int row, col;
            if (i < 120) { int rr = i / 40; row = (rr == 0) ? 0 : 32 + rr; col = i % 40; }
            else         { int j = i - 120; row = 1 + j / 3; int cc = j % 3; col = (cc == 0) ? 0 : 32 + cc; }
            *(half4v*)&As1[row][col][0] = z4;
        }
        // As2: rows {0,17} cols 0..17 ; cols {0,17} rows 1..16 ; ci 0..31 (4xfloat4)
        float4 z = make_float4(0.f, 0.f, 0.f, 0.f);
        for (int i = tid; i < 272; i += 256) {
            int pair = i >> 2, q = i & 3;
            int row, col;
            if      (pair < 18) { row = 0;  col = pair; }
            else if (pair < 36) { row = 17; col = pair - 18; }
            else if (pair < 52) { row = pair - 36 + 1; col = 0; }
            else                { row = pair - 52 + 1; col = 17; }
            *(float4*)&As2[row][col][q * 8] = z;
        }
    }

    // stage x: 4 pixels per thread (12 contiguous floats), rows 1..32 cols 1..32
    {
        int y = tid >> 3, x0 = (tid & 7) * 4;
        const float* src = x + ((long)b * 1024 + y * 32 + x0) * 3;
        float4 f0 = *(const float4*)(src);
        float4 f1 = *(const float4*)(src + 4);
        float4 f2 = *(const float4*)(src + 8);
        half4v h0 = { (_Float16)f0.x, (_Float16)f0.y, (_Float16)f0.z, (_Float16)0.f };
        half4v h1 = { (_Float16)f0.w, (_Float16)f1.x, (_Float16)f1.y, (_Float16)0.f };
        half4v h2 = { (_Float16)f1.z, (_Float16)f1.w, (_Float16)f2.x, (_Float16)0.f };
        half4v h3 = { (_Float16)f2.y, (_Float16)f2.z, (_Float16)f2.w, (_Float16)0.f };
        *(half4v*)&As1[y + 1][x0 + 1][0] = h0;
        *(half4v*)&As1[y + 1][x0 + 2][0] = h1;
        *(half4v*)&As1[y + 1][x0 + 3][0] = h2;
        *(half4v*)&As1[y + 1][x0 + 4][0] = h3;
    }

    half8 bf1[2][2];
#pragma unroll
    for (int p = 0; p < 2; ++p)
#pragma unroll
        for (int nf = 0; nf < 2; ++nf)
            bf1[p][nf] = *(const half8*)(Wt1 + (p * 32 + nf * 16 + l15) * 32 + lq * 8);

    float bv1[2], S1[2], T1[2];
#pragma unroll
    for (int nf = 0; nf < 2; ++nf) {
        int co = nf * 16 + l15;
        bv1[nf] = b1[co];
        float s = rsqrtf(v1[co] + EPS) * g1[co];
        S1[nf] = s;
        T1[nf] = bb1[co] - m1[co] * s;
    }
    __syncthreads();

    // ---- Phase A: conv1 MFMAs (ky-paired) -> pool+relu+BN -> As2 ----
    {
        int y0 = w * 8;
#pragma unroll
        for (int pr = 0; pr < 4; ++pr) {
            int ya = y0 + 2 * pr;
            f32x4 acc[2][2][2];
#pragma unroll
            for (int r = 0; r < 2; ++r)
#pragma unroll
                for (int h = 0; h < 2; ++h)
#pragma unroll
                    for (int nf = 0; nf < 2; ++nf)
                        acc[r][h][nf] = (f32x4){ bv1[nf], bv1[nf], bv1[nf], bv1[nf] };

#pragma unroll
            for (int p = 0; p < 2; ++p)
#pragma unroll
                for (int r = 0; r < 2; ++r)
#pragma unroll
                    for (int h = 0; h < 2; ++h) {
                        const _Float16* ap = &As1[ya + r + 2 * p + lqr][h * 16 + l15 + lqc][0];
                        half4v a0 = *(const half4v*)ap;
                        half4v a1 = *(const half4v*)(ap + 4);
                        half8 af = __builtin_shufflevector(a0, a1, 0, 1, 2, 3, 4, 5, 6, 7);
#pragma unroll
                        for (int nf = 0; nf < 2; ++nf)
                            acc[r][h][nf] = __builtin_amdgcn_mfma_f32_16x16x32_f16(
                                af, bf1[p][nf], acc[r][h][nf], 0, 0, 0);
                    }

            int py = w * 4 + pr;
#pragma unroll
            for (int h = 0; h < 2; ++h)
#pragma unroll
                for (int nf = 0; nf < 2; ++nf) {
                    f32x4 aA = acc[0][h][nf], aB = acc[1][h][nf];
                    float p0 = fmaxf(fmaxf(aA[0], aA[1]), fmaxf(aB[0], aB[1]));
                    float p1 = fmaxf(fmaxf(aA[2], aA[3]), fmaxf(aB[2], aB[3]));
                    p0 = fmaxf(p0, 0.f); p1 = fmaxf(p1, 0.f);
                    p0 = fmaf(p0, S1[nf], T1[nf]);
                    p1 = fmaf(p1, S1[nf], T1[nf]);
                    int px = h * 8 + lq * 2;
                    int co = nf * 16 + l15;
                    As2[py + 1][px + 1][co] = (_Float16)p0;
                    As2[py + 1][px + 2][co] = (_Float16)p1;
                }
        }
    }
    __syncthreads();

    // ---- Phase B: conv2 from As2 ----
    f32x4 acc2[4][4];
#pragma unroll
    for (int nf = 0; nf < 4; ++nf) {
        float bv = b2[nf * 16 + l15];
#pragma unroll
        for (int mf = 0; mf < 4; ++mf)
            acc2[mf][nf] = (f32x4){ bv, bv, bv, bv };
    }

    int row0 = 4 * w;
#pragma unroll
    for (int tap = 0; tap < 9; ++tap) {
        int ky = tap / 3, kx = tap % 3;
        half8 bf[4];
        const _Float16* wb = Wt + ((long)(tap * 64 + l15)) * 32 + lq * 8;
#pragma unroll
        for (int nf = 0; nf < 4; ++nf)
            bf[nf] = *(const half8*)(wb + (long)nf * 16 * 32);
#pragma unroll
        for (int mf = 0; mf < 4; ++mf) {
            const _Float16* ap = &As2[row0 + mf + ky][l15 + kx][lq * 8];
            half8 af = *(const half8*)ap;
#pragma unroll
            for (int nf = 0; nf < 4; ++nf)
                acc2[mf][nf] = __builtin_amdgcn_mfma_f32_16x16x32_f16(
                    af, bf[nf], acc2[mf][nf], 0, 0, 0);
        }
    }

#pragma unroll
    for (int nf = 0; nf < 4; ++nf) {
        int co = nf * 16 + l15;
        float s = rsqrtf(v2[co] + EPS) * g2[co];
        float t2 = bb2[co] - m2[co] * s;
#pragma unroll
        for (int pr = 0; pr < 2; ++pr) {
            int prow = 2 * w + pr;
            f32x4 a0 = acc2[2 * pr][nf];
            f32x4 a1 = acc2[2 * pr + 1][nf];
            float p0 = fmaxf(fmaxf(a0[0], a0[1]), fmaxf(a1[0], a1[1]));
            float p1 = fmaxf(fmaxf(a0[2], a0[3]), fmaxf(a1[2], a1[3]));
            p0 = fmaxf(p0, 0.f);
            p1 = fmaxf(p1, 0.f);
            int ppx = lq * 2;
            long base = (((long)b * 8 + prow) * 8) * 64 + co;
            out[base + (long)(ppx    ) * 64] = (_Float16)fmaf(p0, s, t2);
            out[base + (long)(ppx + 1) * 64] = (_Float16)fmaf(p1, s, t2);
        }
    }
}

// ---------------------------------------------------------------------------
// Kernel 3a: dense 4096 -> 128, split-K x8, f16 MFMA. Partials now f16 (4 MB).
// ---------------------------------------------------------------------------
__global__ __launch_bounds__(256) void k_dense_mfma(
    const _Float16* __restrict__ h2f, const _Float16* __restrict__ Wt2,
    _Float16* __restrict__ pws)
{
    __shared__ __align__(16) _Float16 As[16][264];
    int tid = threadIdx.x;
    int w = tid >> 6, l = tid & 63;
    int l15 = l & 15, lq = l >> 4;
    int brow = blockIdx.x * 16;
    int kbase = blockIdx.y * 512;
    int n0 = w * 32;

    f32x4 acc[2] = { (f32x4){0.f,0.f,0.f,0.f}, (f32x4){0.f,0.f,0.f,0.f} };

    int srow = tid >> 4, sc = (tid & 15) * 16;
#pragma unroll
    for (int k0 = 0; k0 < 512; k0 += 256) {
        __syncthreads();
        const _Float16* src = h2f + (long)(brow + srow) * 4096 + kbase + k0 + sc;
        half8 v0 = *(const half8*)src;
        half8 v1 = *(const half8*)(src + 8);
        *(half8*)(&As[srow][sc])     = v0;
        *(half8*)(&As[srow][sc + 8]) = v1;
        __syncthreads();
#pragma unroll
        for (int kk = 0; kk < 256; kk += 32) {
            half8 af = *(const half8*)(&As[l15][kk + lq * 8]);
#pragma unroll
            for (int nf = 0; nf < 2; ++nf) {
                half8 bf = *(const half8*)(Wt2 + (long)(n0 + nf * 16 + l15) * 4096
                                           + kbase + k0 + kk + lq * 8);
                acc[nf] = __builtin_amdgcn_mfma_f32_16x16x32_f16(af, bf, acc[nf], 0, 0, 0);
            }
        }
    }

    _Float16* pbase = pws + (long)blockIdx.y * 262144;
#pragma unroll
    for (int nf = 0; nf < 2; ++nf) {
        int n = n0 + nf * 16 + l15;
#pragma unroll
        for (int reg = 0; reg < 4; ++reg) {
            int b = brow + lq * 4 + reg;
            pbase[(long)b * 128 + n] = (_Float16)acc[nf][reg];
        }
    }
}

// ---------------------------------------------------------------------------
// Kernel 3b: fused split-K reduce (f16 partials) + bias + relu -> featsH,
// then router MLP + softmax. One block per 8 batch rows (grid 256).
// ---------------------------------------------------------------------------
__global__ __launch_bounds__(256) void k_reduce_router(
    const _Float16* __restrict__ pws, const float* __restrict__ db,
    const float* __restrict__ rW1, const float* __restrict__ rb1,
    const float* __restrict__ rW2, const float* __restrict__ rb2,
    _Float16* __restrict__ featsH, float* __restrict__ probs)
{
    __shared__ float fsm[8][128];
    __shared__ float r1s[8][64];
    int tid = threadIdx.x;
    int brow = blockIdx.x * 8;
    int r = tid >> 5, c0 = (tid & 31) * 4;

    float acc[4];
#pragma unroll
    for (int j = 0; j < 4; ++j) acc[j] = db[c0 + j];
    long base = (long)(brow + r) * 128 + c0;
#pragma unroll
    for (int kc = 0; kc < 8; ++kc) {
        half4v v0 = *(const half4v*)(pws + (long)kc * 262144 + base);
#pragma unroll
        for (int j = 0; j < 4; ++j) acc[j] += (float)v0[j];
    }
    half4v hv;
#pragma unroll
    for (int j = 0; j < 4; ++j) {
        float val = fmaxf(acc[j], 0.f);
        fsm[r][c0 + j] = val;
        hv[j] = (_Float16)val;
    }
    *(half4v*)(featsH + base) = hv;
    __syncthreads();

    {
        int h = tid & 63, bg = tid >> 6;
        float a[2];
#pragma unroll
        for (int i = 0; i < 2; ++i) a[i] = rb1[h];
        for (int d = 0; d < 128; ++d) {
            float wgt = rW1[d * 64 + h];
#pragma unroll
            for (int i = 0; i < 2; ++i) a[i] += fsm[bg * 2 + i][d] * wgt;
        }
#pragma unroll
        for (int i = 0; i < 2; ++i) r1s[bg * 2 + i][h] = fmaxf(a[i], 0.f);
    }
    __syncthreads();

    if (tid < 128) {
        int b = tid >> 4, e = tid & 15;
        float a = rb2[e];
#pragma unroll 8
        for (int k = 0; k < 64; ++k) a += r1s[b][k] * rW2[k * 16 + e];
        float mx = a;
#pragma unroll
        for (int off = 1; off < 16; off <<= 1)
            mx = fmaxf(mx, __shfl_xor(mx, off, 16));
        float ex = __expf(a - mx);
        float s = ex;
#pragma unroll
        for (int off = 1; off < 16; off <<= 1)
            s += __shfl_xor(s, off, 16);
        probs[(long)(brow + b) * 16 + e] = ex / s;
    }
}

// ---------------------------------------------------------------------------
// Kernel 5: fused expert chain, f16 MFMA — 8-wave blocks. (r13)
// ---------------------------------------------------------------------------
__global__ __launch_bounds__(512) void k_expert_mfma(
    const _Float16* __restrict__ featsH,
    const _Float16* __restrict__ eW1t, const float* __restrict__ eb1,
    const float* __restrict__ g,  const float* __restrict__ bb,
    const float* __restrict__ m,  const float* __restrict__ v,
    const _Float16* __restrict__ eW2t, const float* __restrict__ eb2,
    const _Float16* __restrict__ eW3p, const float* __restrict__ eb3,
    float* __restrict__ e3p)
{
    __shared__ __align__(16) _Float16 fsH[64][136];
    __shared__ __align__(16) _Float16 h1sH[64][136];
    __shared__ __align__(16) _Float16 h2sH[64][72];
    int e = blockIdx.x, bt = blockIdx.y;
    int tid = threadIdx.x;
    int w = tid >> 6, l = tid & 63, l15 = l & 15, lq = l >> 4;
    int brow = bt * 64;
    int m0 = (w & 3) * 16;
    int nh = w >> 2;

#pragma unroll
    for (int it = 0; it < 2; ++it) {
        int idx = it * 512 + tid;
        int r = idx >> 4, c = (idx & 15) * 8;
        *(half8*)&fsH[r][c] = *(const half8*)(featsH + (long)(brow + r) * 128 + c);
    }
    __syncthreads();

    {
        half8 af[4];
#pragma unroll
        for (int kq = 0; kq < 4; ++kq)
            af[kq] = *(const half8*)&fsH[m0 + l15][kq * 32 + lq * 8];
        const _Float16* B1 = eW1t + (long)e * 16384 + (long)nh * 8192 + l15 * 128 + lq * 8;
        f32x4 acc[4];
#pragma unroll
        for (int nf = 0; nf < 4; ++nf) {
            float bv = eb1[e * 128 + nh * 64 + nf * 16 + l15];
            acc[nf] = (f32x4){ bv, bv, bv, bv };
        }
#pragma unroll
        for (int nf = 0; nf < 4; ++nf)
#pragma unroll
            for (int kq = 0; kq < 4; ++kq) {
                half8 bfv = *(const half8*)(B1 + nf * 2048 + kq * 32);
                acc[nf] = __builtin_amdgcn_mfma_f32_16x16x32_f16(af[kq], bfv, acc[nf], 0, 0, 0);
            }
#pragma unroll
        for (int nf = 0; nf < 4; ++nf) {
            int h = nh * 64 + nf * 16 + l15;
            float gg = g[e * 128 + h], bbv = bb[e * 128 + h], mm = m[e * 128 + h];
            float iv = rsqrtf(v[e * 128 + h] + EPS);
#pragma unroll
            for (int reg = 0; reg < 4; ++reg) {
                float val = fmaxf(acc[nf][reg], 0.f);
                h1sH[m0 + lq * 4 + reg][h] = (_Float16)((val - mm) * iv * gg + bbv);
            }
        }
    }
    __syncthreads();

    {
        half8 af[4];
#pragma unroll
        for (int kq = 0; kq < 4; ++kq)
            af[kq] = *(const half8*)&h1sH[m0 + l15][kq * 32 + lq * 8];
        const _Float16* B2 = eW2t + (long)e * 8192 + (long)nh * 4096 + l15 * 128 + lq * 8;
        f32x4 acc[2];
#pragma unroll
        for (int nf = 0; nf < 2; ++nf) {
            float bv = eb2[e * 64 + nh * 32 + nf * 16 + l15];
            acc[nf] = (f32x4){ bv, bv, bv, bv };
        }
#pragma unroll
        for (int nf = 0; nf < 2; ++nf)
#pragma unroll
            for (int kq = 0; kq < 4; ++kq) {
                half8 bfv = *(const half8*)(B2 + nf * 2048 + kq * 32);
                acc[nf] = __builtin_amdgcn_mfma_f32_16x16x32_f16(af[kq], bfv, acc[nf], 0, 0, 0);
            }
#pragma unroll
        for (int nf = 0; nf < 2; ++nf)
#pragma unroll
            for (int reg = 0; reg < 4; ++reg)
                h2sH[m0 + lq * 4 + reg][nh * 32 + nf * 16 + l15] =
                    (_Float16)fmaxf(acc[nf][reg], 0.f);
    }
    __syncthreads();

    if (nh == 0) {
        half8 af[2];
#pragma unroll
        for (int kq = 0; kq < 2; ++kq)
            af[kq] = *(const half8*)&h2sH[m0 + l15][kq * 32 + lq * 8];
        const _Float16* B3 = eW3p + (long)e * 1024 + l15 * 64 + lq * 8;
        float bv = (l15 < 10) ? eb3[e * 10 + l15] : 0.f;
        f32x4 acc = (f32x4){ bv, bv, bv, bv };
#pragma unroll
        for (int kq = 0; kq < 2; ++kq) {
            half8 bfv = *(const half8*)(B3 + kq * 32);
            acc = __builtin_amdgcn_mfma_f32_16x16x32_f16(af[kq], bfv, acc, 0, 0, 0);
        }
#pragma unroll
        for (int reg = 0; reg < 4; ++reg) {
            int b = brow + m0 + lq * 4 + reg;
            e3p[((long)e * 2048 + b) * 16 + l15] = acc[reg];
        }
    }
}

// ---------------------------------------------------------------------------
// Kernel 6: combine.  out[b][c] = sum_e probs[b][e] * e3p[e][b][c]
// ---------------------------------------------------------------------------
__global__ __launch_bounds__(256) void k_combine(
    const float* __restrict__ e3p, const float* __restrict__ probs,
    float* __restrict__ out)
{
    int t = blockIdx.x * blockDim.x + threadIdx.x;
    if (t >= 2048 * 10) return;
    int b = t / 10, c = t % 10;
    float acc = 0.f;
#pragma unroll
    for (int e = 0; e < 16; ++e)
        acc += probs[(long)b * 16 + e] * e3p[((long)e * 2048 + b) * 16 + c];
    out[t] = acc;
}

// ---------------------------------------------------------------------------
extern "C" void kernel_launch(void* const* d_in, const int* in_sizes, int n_in,
                              void* d_out, int out_size, void* d_ws, size_t ws_size,
                              hipStream_t stream)
{
    const float* x    = (const float*)d_in[0];
    const float* cW1  = (const float*)d_in[1];
    const float* cb1  = (const float*)d_in[2];
    const float* bn1g = (const float*)d_in[3];
    const float* bn1b = (const float*)d_in[4];
    const float* bn1m = (const float*)d_in[5];
    const float* bn1v = (const float*)d_in[6];
    const float* cW2  = (const float*)d_in[7];
    const float* cb2  = (const float*)d_in[8];
    const float* bn2g = (const float*)d_in[9];
    const float* bn2b = (const float*)d_in[10];
    const float* bn2m = (const float*)d_in[11];
    const float* bn2v = (const float*)d_in[12];
    const float* dW   = (const float*)d_in[13];
    const float* db   = (const float*)d_in[14];
    const float* rW1  = (const float*)d_in[15];
    const float* rb1  = (const float*)d_in[16];
    const float* rW2  = (const float*)d_in[17];
    const float* rb2  = (const float*)d_in[18];
    const float* eW1  = (const float*)d_in[19];
    const float* eb1  = (const float*)d_in[20];
    const float* ebng = (const float*)d_in[21];
    const float* ebnb = (const float*)d_in[22];
    const float* ebnm = (const float*)d_in[23];
    const float* ebnv = (const float*)d_in[24];
    const float* eW2  = (const float*)d_in[25];
    const float* eb2  = (const float*)d_in[26];
    const float* eW3  = (const float*)d_in[27];
    const float* eb3  = (const float*)d_in[28];

    float* ws    = (float*)d_ws;
    // --- region 1 (recycled): e3p + featsH ---
    float* h1reg = ws;
    float* e3p   = h1reg;                                  // [0 .. 524,288) floats
    _Float16* featsH = (_Float16*)(h1reg + 524288);        // 262,144 f16
    // --- region 2: h2reg ---
    float* h2reg = h1reg + 16777216;
    _Float16* h2f = (_Float16*)h2reg;                      // conv2 out f16 [2048][4096]
    _Float16* Wt2 = (_Float16*)(h2reg + 4194304);          // dense weights f16 [128][4096]
    // --- region 3: small tensors ---
    float* probs = h2reg + 8388608;
    float* ewreg = probs + 32768;
    _Float16* eW1t = (_Float16*)ewreg;             // 262,144 f16
    _Float16* eW2t = eW1t + 262144;                // 131,072 f16
    _Float16* eW3p = eW2t + 131072;                //  16,384 f16
    _Float16* Wt   = eW3p + 16384;                 //  18,432 f16 (conv2 w)
    _Float16* Wt1  = Wt + 18432;                   //   3,072 f16 slot (conv1 w)
    // --- region 4: dense split-K partials f16 [8][2048][128] = 4 MB ---
    _Float16* pws = (_Float16*)(ewreg + 262144);
    float* out   = (float*)d_out;

    k_wprep_all<<<244, 256, 0, stream>>>(dW, Wt2, eW1, eW1t, eW2, eW2t,
                                         cW1, Wt1, cW2, Wt, eW3, eW3p);
    k_conv12<<<2048, 256, 0, stream>>>(x, Wt1, cb1, bn1g, bn1b, bn1m, bn1v,
                                       Wt, cb2, bn2g, bn2b, bn2m, bn2v, h2f);
    {
        dim3 grid(128, 8);
        k_dense_mfma<<<grid, 256, 0, stream>>>(h2f, Wt2, pws);
    }
    k_reduce_router<<<256, 256, 0, stream>>>(pws, db, rW1, rb1, rW2, rb2,
                                             featsH, probs);
    {
        dim3 grid(16, 32);
        k_expert_mfma<<<grid, 512, 0, stream>>>(featsH, eW1t, eb1, ebng, ebnb, ebnm, ebnv,
                                                eW2t, eb2, eW3p, eb3, e3p);
    }
    k_combine<<<80, 256, 0, stream>>>(e3p, probs, out);
}

// Round 17
// 85.040 us; speedup vs baseline: 1.2705x; 1.0176x over previous
//
#include <hip/hip_runtime.h>

#define EPS 1e-3f

typedef _Float16 half8 __attribute__((ext_vector_type(8)));
typedef _Float16 half4v __attribute__((ext_vector_type(4)));
typedef float f32x4 __attribute__((ext_vector_type(4)));

// ---------------------------------------------------------------------------
// Merged weight prep (single dispatch), branch by block range (r13).
// ---------------------------------------------------------------------------
__global__ __launch_bounds__(256) void k_wprep_all(
    const float* __restrict__ dW,  _Float16* __restrict__ Wt2,
    const float* __restrict__ eW1, _Float16* __restrict__ eW1t,
    const float* __restrict__ eW2, _Float16* __restrict__ eW2t,
    const float* __restrict__ cW1, _Float16* __restrict__ Wt1,
    const float* __restrict__ cW2, _Float16* __restrict__ Wt,
    const float* __restrict__ eW3, _Float16* __restrict__ eW3p)
{
    __shared__ _Float16 lsbuf[16640];
    int bx = blockIdx.x, tid = threadIdx.x;

    if (bx < 64) {
        auto lt = (_Float16(*)[137])lsbuf;       // [64][137]
        int kb = bx * 64;
        int c = tid & 127, r2 = tid >> 7;
#pragma unroll
        for (int it = 0; it < 32; ++it) {
            int r = it * 2 + r2;
            lt[r][c] = (_Float16)dW[(long)(kb + r) * 128 + c];
        }
        __syncthreads();
#pragma unroll
        for (int it = 0; it < 4; ++it) {
            int chunk = it * 256 + tid;
            int n = chunk >> 3, kc = (chunk & 7) * 8;
            half8 v;
#pragma unroll
            for (int j = 0; j < 8; ++j) v[j] = lt[kc + j][n];
            *(half8*)(Wt2 + (long)n * 4096 + kb + kc) = v;
        }
    } else if (bx < 80) {
        auto lt = (_Float16(*)[130])lsbuf;       // [128][130]
        int e = bx - 64;
        const float* src = eW1 + (long)e * 16384;
#pragma unroll
        for (int it = 0; it < 64; ++it) {
            int idx = it * 256 + tid;
            lt[idx >> 7][idx & 127] = (_Float16)src[idx];
        }
        __syncthreads();
        _Float16* dst = eW1t + (long)e * 16384;
#pragma unroll
        for (int it = 0; it < 64; ++it) {
            int idx = it * 256 + tid;            // idx = h*128 + d
            dst[idx] = lt[idx & 127][idx >> 7];
        }
    } else if (bx < 96) {
        auto lt = (_Float16(*)[66])lsbuf;        // [128][66]
        int e = bx - 80;
        const float* src = eW2 + (long)e * 8192;
#pragma unroll
        for (int it = 0; it < 32; ++it) {
            int idx = it * 256 + tid;
            lt[idx >> 6][idx & 63] = (_Float16)src[idx];
        }
        __syncthreads();
        _Float16* dst = eW2t + (long)e * 8192;
#pragma unroll
        for (int it = 0; it < 32; ++it) {
            int idx = it * 256 + tid;            // idx = n*128 + d
            dst[idx] = lt[idx & 127][idx >> 7];
        }
    } else {
        int t = (bx - 96) * 256 + tid;
        if (t < 2048) {
            int k = t & 31, co = (t >> 5) & 31, p = t >> 10;
            int kyin = (k >> 4) & 1, kxp = (k >> 2) & 3, ci = k & 3;
            int ky = 2 * p + kyin;
            float val = (ky < 3 && kxp < 3 && ci < 3)
                        ? cW1[((ky * 3 + kxp) * 3 + ci) * 32 + co] : 0.f;
            Wt1[t] = (_Float16)val;
        } else if (t >= 3072 && t < 3072 + 18432) {
            int u = t - 3072;
            int co = u & 63;
            int rest = u >> 6;
            int ci = rest & 31, tap = rest >> 5;
            Wt[(tap * 64 + co) * 32 + ci] = (_Float16)cW2[u];
        } else if (t >= 21504 && t < 21504 + 16384) {
            int u = t - 21504;
            int k = u & 63, n = (u >> 6) & 15, e = u >> 10;
            float val = (n < 10) ? eW3[(e * 64 + k) * 10 + n] : 0.f;
            eW3p[(e * 16 + n) * 64 + k] = (_Float16)val;
        }
    }
}

// ---------------------------------------------------------------------------
// conv12 phase helpers (bodies identical to r16-verified code).
// ---------------------------------------------------------------------------
__device__ __forceinline__ void conv12_phaseA(
    _Float16 (*As1)[40][4], _Float16 (*As2)[18][40],
    const half8 bf1[2][2], const float bv1[2], const float S1[2], const float T1[2],
    int w, int l15, int lq, int lqr, int lqc)
{
    int y0 = w * 8;
#pragma unroll
    for (int pr = 0; pr < 4; ++pr) {
        int ya = y0 + 2 * pr;
        f32x4 acc[2][2][2];
#pragma unroll
        for (int r = 0; r < 2; ++r)
#pragma unroll
            for (int h = 0; h < 2; ++h)
#pragma unroll
                for (int nf = 0; nf < 2; ++nf)
                    acc[r][h][nf] = (f32x4){ bv1[nf], bv1[nf], bv1[nf], bv1[nf] };

#pragma unroll
        for (int p = 0; p < 2; ++p)
#pragma unroll
            for (int r = 0; r < 2; ++r)
#pragma unroll
                for (int h = 0; h < 2; ++h) {
                    const _Float16* ap = &As1[ya + r + 2 * p + lqr][h * 16 + l15 + lqc][0];
                    half4v a0 = *(const half4v*)ap;
                    half4v a1 = *(const half4v*)(ap + 4);
                    half8 af = __builtin_shufflevector(a0, a1, 0, 1, 2, 3, 4, 5, 6, 7);
#pragma unroll
                    for (int nf = 0; nf < 2; ++nf)
                        acc[r][h][nf] = __builtin_amdgcn_mfma_f32_16x16x32_f16(
                            af, bf1[p][nf], acc[r][h][nf], 0, 0, 0);
                }

        int py = w * 4 + pr;
#pragma unroll
        for (int h = 0; h < 2; ++h)
#pragma unroll
            for (int nf = 0; nf < 2; ++nf) {
                f32x4 aA = acc[0][h][nf], aB = acc[1][h][nf];
                float p0 = fmaxf(fmaxf(aA[0], aA[1]), fmaxf(aB[0], aB[1]));
                float p1 = fmaxf(fmaxf(aA[2], aA[3]), fmaxf(aB[2], aB[3]));
                p0 = fmaxf(p0, 0.f); p1 = fmaxf(p1, 0.f);
                p0 = fmaf(p0, S1[nf], T1[nf]);
                p1 = fmaf(p1, S1[nf], T1[nf]);
                int px = h * 8 + lq * 2;
                int co = nf * 16 + l15;
                As2[py + 1][px + 1][co] = (_Float16)p0;
                As2[py + 1][px + 2][co] = (_Float16)p1;
            }
    }
}

__device__ __forceinline__ void conv12_phaseB(
    _Float16 (*As2)[18][40], const _Float16* __restrict__ Wt,
    const float bv2[4], const float S2[4], const float T2[4],
    _Float16* __restrict__ out, long b, int w, int l15, int lq)
{
    f32x4 acc2[4][4];
#pragma unroll
    for (int nf = 0; nf < 4; ++nf)
#pragma unroll
        for (int mf = 0; mf < 4; ++mf)
            acc2[mf][nf] = (f32x4){ bv2[nf], bv2[nf], bv2[nf], bv2[nf] };

    int row0 = 4 * w;
#pragma unroll
    for (int tap = 0; tap < 9; ++tap) {
        int ky = tap / 3, kx = tap % 3;
        half8 bf[4];
        const _Float16* wb = Wt + ((long)(tap * 64 + l15)) * 32 + lq * 8;
#pragma unroll
        for (int nf = 0; nf < 4; ++nf)
            bf[nf] = *(const half8*)(wb + (long)nf * 16 * 32);
#pragma unroll
        for (int mf = 0; mf < 4; ++mf) {
            const _Float16* ap = &As2[row0 + mf + ky][l15 + kx][lq * 8];
            half8 af = *(const half8*)ap;
#pragma unroll
            for (int nf = 0; nf < 4; ++nf)
                acc2[mf][nf] = __builtin_amdgcn_mfma_f32_16x16x32_f16(
                    af, bf[nf], acc2[mf][nf], 0, 0, 0);
        }
    }

#pragma unroll
    for (int nf = 0; nf < 4; ++nf) {
        int co = nf * 16 + l15;
#pragma unroll
        for (int pr = 0; pr < 2; ++pr) {
            int prow = 2 * w + pr;
            f32x4 a0 = acc2[2 * pr][nf];
            f32x4 a1 = acc2[2 * pr + 1][nf];
            float p0 = fmaxf(fmaxf(a0[0], a0[1]), fmaxf(a1[0], a1[1]));
            float p1 = fmaxf(fmaxf(a0[2], a0[3]), fmaxf(a1[2], a1[3]));
            p0 = fmaxf(p0, 0.f);
            p1 = fmaxf(p1, 0.f);
            int ppx = lq * 2;
            long base = ((b * 8 + prow) * 8) * 64 + co;
            out[base + (long)(ppx    ) * 64] = (_Float16)fmaf(p0, S2[nf], T2[nf]);
            out[base + (long)(ppx + 1) * 64] = (_Float16)fmaf(p1, S2[nf], T2[nf]);
        }
    }
}

// ---------------------------------------------------------------------------
// Fused conv1+conv2, 2 images per block, software-pipelined (T14 split):
// img1's global loads issue before Phase B(img0); LDS write after.
// Grid 1024 = exactly 4 blocks/CU (37 KB LDS), all resident.
// ---------------------------------------------------------------------------
__global__ __launch_bounds__(256) void k_conv12(
    const float* __restrict__ x, const _Float16* __restrict__ Wt1,
    const float* __restrict__ b1, const float* __restrict__ g1,
    const float* __restrict__ bb1, const float* __restrict__ m1,
    const float* __restrict__ v1,
    const _Float16* __restrict__ Wt,
    const float* __restrict__ b2, const float* __restrict__ g2,
    const float* __restrict__ bb2, const float* __restrict__ m2,
    const float* __restrict__ v2,
    _Float16* __restrict__ out)
{
    __shared__ __align__(16) _Float16 As1[35][40][4];
    __shared__ __align__(16) _Float16 As2[18][18][40];
    int tid = threadIdx.x;
    long img0 = (long)blockIdx.x * 2, img1 = img0 + 1;
    int w = tid >> 6, l = tid & 63;
    int l15 = l & 15, lq = l >> 4;
    int lqr = lq >> 1, lqc = (lq & 1) * 2;

    // halo-only zeroing (r16): disjoint from interior writes.
    {
        half4v z4 = { (_Float16)0.f, (_Float16)0.f, (_Float16)0.f, (_Float16)0.f };
        for (int i = tid; i < 216; i += 256) {
            int row, col;
            if (i < 120) { int rr = i / 40; row = (rr == 0) ? 0 : 32 + rr; col = i % 40; }
            else         { int j = i - 120; row = 1 + j / 3; int cc = j % 3; col = (cc == 0) ? 0 : 32 + cc; }
            *(half4v*)&As1[row][col][0] = z4;
        }
        float4 z = make_float4(0.f, 0.f, 0.f, 0.f);
        for (int i = tid; i < 272; i += 256) {
            int pair = i >> 2, q = i & 3;
            int row, col;
            if      (pair < 18) { row = 0;  col = pair; }
            else if (pair < 36) { row = 17; col = pair - 18; }
            else if (pair < 52) { row = pair - 36 + 1; col = 0; }
            else                { row = pair - 52 + 1; col = 17; }
            *(float4*)&As2[row][col][q * 8] = z;
        }
    }

    int sy = tid >> 3, sx0 = (tid & 7) * 4;

    // stage img0
    {
        const float* src = x + (img0 * 1024 + sy * 32 + sx0) * 3;
        float4 f0 = *(const float4*)(src);
        float4 f1 = *(const float4*)(src + 4);
        float4 f2 = *(const float4*)(src + 8);
        half4v h0 = { (_Float16)f0.x, (_Float16)f0.y, (_Float16)f0.z, (_Float16)0.f };
        half4v h1 = { (_Float16)f0.w, (_Float16)f1.x, (_Float16)f1.y, (_Float16)0.f };
        half4v h2 = { (_Float16)f1.z, (_Float16)f1.w, (_Float16)f2.x, (_Float16)0.f };
        half4v h3 = { (_Float16)f2.y, (_Float16)f2.z, (_Float16)f2.w, (_Float16)0.f };
        *(half4v*)&As1[sy + 1][sx0 + 1][0] = h0;
        *(half4v*)&As1[sy + 1][sx0 + 2][0] = h1;
        *(half4v*)&As1[sy + 1][sx0 + 3][0] = h2;
        *(half4v*)&As1[sy + 1][sx0 + 4][0] = h3;
    }

    // weights + BN constants (hoisted once per block)
    half8 bf1[2][2];
#pragma unroll
    for (int p = 0; p < 2; ++p)
#pragma unroll
        for (int nf = 0; nf < 2; ++nf)
            bf1[p][nf] = *(const half8*)(Wt1 + (p * 32 + nf * 16 + l15) * 32 + lq * 8);

    float bv1[2], S1[2], T1[2];
#pragma unroll
    for (int nf = 0; nf < 2; ++nf) {
        int co = nf * 16 + l15;
        bv1[nf] = b1[co];
        float s = rsqrtf(v1[co] + EPS) * g1[co];
        S1[nf] = s;
        T1[nf] = bb1[co] - m1[co] * s;
    }
    float bv2[4], S2[4], T2[4];
#pragma unroll
    for (int nf = 0; nf < 4; ++nf) {
        int co = nf * 16 + l15;
        bv2[nf] = b2[co];
        float s = rsqrtf(v2[co] + EPS) * g2[co];
        S2[nf] = s;
        T2[nf] = bb2[co] - m2[co] * s;
    }
    __syncthreads();

    // Phase A (img0)
    conv12_phaseA(As1, As2, bf1, bv1, S1, T1, w, l15, lq, lqr, lqc);
    __syncthreads();

    // issue img1 loads early (T14 split)
    float4 g0, g1v, g2v;
    {
        const float* src = x + (img1 * 1024 + sy * 32 + sx0) * 3;
        g0  = *(const float4*)(src);
        g1v = *(const float4*)(src + 4);
        g2v = *(const float4*)(src + 8);
    }
    // Phase B (img0) computes while img1 loads are in flight
    conv12_phaseB(As2, Wt, bv2, S2, T2, out, img0, w, l15, lq);
    // write img1 into As1 (vmcnt wait hidden under Phase B)
    {
        half4v h0 = { (_Float16)g0.x,  (_Float16)g0.y,  (_Float16)g0.z,  (_Float16)0.f };
        half4v h1 = { (_Float16)g0.w,  (_Float16)g1v.x, (_Float16)g1v.y, (_Float16)0.f };
        half4v h2 = { (_Float16)g1v.z, (_Float16)g1v.w, (_Float16)g2v.x, (_Float16)0.f };
        half4v h3 = { (_Float16)g2v.y, (_Float16)g2v.z, (_Float16)g2v.w, (_Float16)0.f };
        *(half4v*)&As1[sy + 1][sx0 + 1][0] = h0;
        *(half4v*)&As1[sy + 1][sx0 + 2][0] = h1;
        *(half4v*)&As1[sy + 1][sx0 + 3][0] = h2;
        *(half4v*)&As1[sy + 1][sx0 + 4][0] = h3;
    }
    __syncthreads();

    // Phase A (img1)
    conv12_phaseA(As1, As2, bf1, bv1, S1, T1, w, l15, lq, lqr, lqc);
    __syncthreads();

    // Phase B (img1)
    conv12_phaseB(As2, Wt, bv2, S2, T2, out, img1, w, l15, lq);
}

// ---------------------------------------------------------------------------
// Kernel 3a: dense 4096 -> 128, split-K x8, f16 MFMA. Partials f16 (4 MB).
// ---------------------------------------------------------------------------
__global__ __launch_bounds__(256) void k_dense_mfma(
    const _Float16* __restrict__ h2f, const _Float16* __restrict__ Wt2,
    _Float16* __restrict__ pws)
{
    __shared__ __align__(16) _Float16 As[16][264];
    int tid = threadIdx.x;
    int w = tid >> 6, l = tid & 63;
    int l15 = l & 15, lq = l >> 4;
    int brow = blockIdx.x * 16;
    int kbase = blockIdx.y * 512;
    int n0 = w * 32;

    f32x4 acc[2] = { (f32x4){0.f,0.f,0.f,0.f}, (f32x4){0.f,0.f,0.f,0.f} };

    int srow = tid >> 4, sc = (tid & 15) * 16;
#pragma unroll
    for (int k0 = 0; k0 < 512; k0 += 256) {
        __syncthreads();
        const _Float16* src = h2f + (long)(brow + srow) * 4096 + kbase + k0 + sc;
        half8 v0 = *(const half8*)src;
        half8 v1 = *(const half8*)(src + 8);
        *(half8*)(&As[srow][sc])     = v0;
        *(half8*)(&As[srow][sc + 8]) = v1;
        __syncthreads();
#pragma unroll
        for (int kk = 0; kk < 256; kk += 32) {
            half8 af = *(const half8*)(&As[l15][kk + lq * 8]);
#pragma unroll
            for (int nf = 0; nf < 2; ++nf) {
                half8 bf = *(const half8*)(Wt2 + (long)(n0 + nf * 16 + l15) * 4096
                                           + kbase + k0 + kk + lq * 8);
                acc[nf] = __builtin_amdgcn_mfma_f32_16x16x32_f16(af, bf, acc[nf], 0, 0, 0);
            }
        }
    }

    _Float16* pbase = pws + (long)blockIdx.y * 262144;
#pragma unroll
    for (int nf = 0; nf < 2; ++nf) {
        int n = n0 + nf * 16 + l15;
#pragma unroll
        for (int reg = 0; reg < 4; ++reg) {
            int b = brow + lq * 4 + reg;
            pbase[(long)b * 128 + n] = (_Float16)acc[nf][reg];
        }
    }
}

// ---------------------------------------------------------------------------
// Kernel 3b: fused split-K reduce (f16 partials) + bias + relu -> featsH,
// then router MLP + softmax. One block per 8 batch rows (grid 256).
// ---------------------------------------------------------------------------
__global__ __launch_bounds__(256) void k_reduce_router(
    const _Float16* __restrict__ pws, const float* __restrict__ db,
    const float* __restrict__ rW1, const float* __restrict__ rb1,
    const float* __restrict__ rW2, const float* __restrict__ rb2,
    _Float16* __restrict__ featsH, float* __restrict__ probs)
{
    __shared__ float fsm[8][128];
    __shared__ float r1s[8][64];
    int tid = threadIdx.x;
    int brow = blockIdx.x * 8;
    int r = tid >> 5, c0 = (tid & 31) * 4;

    float acc[4];
#pragma unroll
    for (int j = 0; j < 4; ++j) acc[j] = db[c0 + j];
    long base = (long)(brow + r) * 128 + c0;
#pragma unroll
    for (int kc = 0; kc < 8; ++kc) {
        half4v v0 = *(const half4v*)(pws + (long)kc * 262144 + base);
#pragma unroll
        for (int j = 0; j < 4; ++j) acc[j] += (float)v0[j];
    }
    half4v hv;
#pragma unroll
    for (int j = 0; j < 4; ++j) {
        float val = fmaxf(acc[j], 0.f);
        fsm[r][c0 + j] = val;
        hv[j] = (_Float16)val;
    }
    *(half4v*)(featsH + base) = hv;
    __syncthreads();

    {
        int h = tid & 63, bg = tid >> 6;
        float a[2];
#pragma unroll
        for (int i = 0; i < 2; ++i) a[i] = rb1[h];
        for (int d = 0; d < 128; ++d) {
            float wgt = rW1[d * 64 + h];
#pragma unroll
            for (int i = 0; i < 2; ++i) a[i] += fsm[bg * 2 + i][d] * wgt;
        }
#pragma unroll
        for (int i = 0; i < 2; ++i) r1s[bg * 2 + i][h] = fmaxf(a[i], 0.f);
    }
    __syncthreads();

    if (tid < 128) {
        int b = tid >> 4, e = tid & 15;
        float a = rb2[e];
#pragma unroll 8
        for (int k = 0; k < 64; ++k) a += r1s[b][k] * rW2[k * 16 + e];
        float mx = a;
#pragma unroll
        for (int off = 1; off < 16; off <<= 1)
            mx = fmaxf(mx, __shfl_xor(mx, off, 16));
        float ex = __expf(a - mx);
        float s = ex;
#pragma unroll
        for (int off = 1; off < 16; off <<= 1)
            s += __shfl_xor(s, off, 16);
        probs[(long)(brow + b) * 16 + e] = ex / s;
    }
}

// ---------------------------------------------------------------------------
// Kernel 5: fused expert chain, f16 MFMA — 8-wave blocks. (r13)
// ---------------------------------------------------------------------------
__global__ __launch_bounds__(512) void k_expert_mfma(
    const _Float16* __restrict__ featsH,
    const _Float16* __restrict__ eW1t, const float* __restrict__ eb1,
    const float* __restrict__ g,  const float* __restrict__ bb,
    const float* __restrict__ m,  const float* __restrict__ v,
    const _Float16* __restrict__ eW2t, const float* __restrict__ eb2,
    const _Float16* __restrict__ eW3p, const float* __restrict__ eb3,
    float* __restrict__ e3p)
{
    __shared__ __align__(16) _Float16 fsH[64][136];
    __shared__ __align__(16) _Float16 h1sH[64][136];
    __shared__ __align__(16) _Float16 h2sH[64][72];
    int e = blockIdx.x, bt = blockIdx.y;
    int tid = threadIdx.x;
    int w = tid >> 6, l = tid & 63, l15 = l & 15, lq = l >> 4;
    int brow = bt * 64;
    int m0 = (w & 3) * 16;
    int nh = w >> 2;

#pragma unroll
    for (int it = 0; it < 2; ++it) {
        int idx = it * 512 + tid;
        int r = idx >> 4, c = (idx & 15) * 8;
        *(half8*)&fsH[r][c] = *(const half8*)(featsH + (long)(brow + r) * 128 + c);
    }
    __syncthreads();

    {
        half8 af[4];
#pragma unroll
        for (int kq = 0; kq < 4; ++kq)
            af[kq] = *(const half8*)&fsH[m0 + l15][kq * 32 + lq * 8];
        const _Float16* B1 = eW1t + (long)e * 16384 + (long)nh * 8192 + l15 * 128 + lq * 8;
        f32x4 acc[4];
#pragma unroll
        for (int nf = 0; nf < 4; ++nf) {
            float bv = eb1[e * 128 + nh * 64 + nf * 16 + l15];
            acc[nf] = (f32x4){ bv, bv, bv, bv };
        }
#pragma unroll
        for (int nf = 0; nf < 4; ++nf)
#pragma unroll
            for (int kq = 0; kq < 4; ++kq) {
                half8 bfv = *(const half8*)(B1 + nf * 2048 + kq * 32);
                acc[nf] = __builtin_amdgcn_mfma_f32_16x16x32_f16(af[kq], bfv, acc[nf], 0, 0, 0);
            }
#pragma unroll
        for (int nf = 0; nf < 4; ++nf) {
            int h = nh * 64 + nf * 16 + l15;
            float gg = g[e * 128 + h], bbv = bb[e * 128 + h], mm = m[e * 128 + h];
            float iv = rsqrtf(v[e * 128 + h] + EPS);
#pragma unroll
            for (int reg = 0; reg < 4; ++reg) {
                float val = fmaxf(acc[nf][reg], 0.f);
                h1sH[m0 + lq * 4 + reg][h] = (_Float16)((val - mm) * iv * gg + bbv);
            }
        }
    }
    __syncthreads();

    {
        half8 af[4];
#pragma unroll
        for (int kq = 0; kq < 4; ++kq)
            af[kq] = *(const half8*)&h1sH[m0 + l15][kq * 32 + lq * 8];
        const _Float16* B2 = eW2t + (long)e * 8192 + (long)nh * 4096 + l15 * 128 + lq * 8;
        f32x4 acc[2];
#pragma unroll
        for (int nf = 0; nf < 2; ++nf) {
            float bv = eb2[e * 64 + nh * 32 + nf * 16 + l15];
            acc[nf] = (f32x4){ bv, bv, bv, bv };
        }
#pragma unroll
        for (int nf = 0; nf < 2; ++nf)
#pragma unroll
            for (int kq = 0; kq < 4; ++kq) {
                half8 bfv = *(const half8*)(B2 + nf * 2048 + kq * 32);
                acc[nf] = __builtin_amdgcn_mfma_f32_16x16x32_f16(af[kq], bfv, acc[nf], 0, 0, 0);
            }
#pragma unroll
        for (int nf = 0; nf < 2; ++nf)
#pragma unroll
            for (int reg = 0; reg < 4; ++reg)
                h2sH[m0 + lq * 4 + reg][nh * 32 + nf * 16 + l15] =
                    (_Float16)fmaxf(acc[nf][reg], 0.f);
    }
    __syncthreads();

    if (nh == 0) {
        half8 af[2];
#pragma unroll
        for (int kq = 0; kq < 2; ++kq)
            af[kq] = *(const half8*)&h2sH[m0 + l15][kq * 32 + lq * 8];
        const _Float16* B3 = eW3p + (long)e * 1024 + l15 * 64 + lq * 8;
        float bv = (l15 < 10) ? eb3[e * 10 + l15] : 0.f;
        f32x4 acc = (f32x4){ bv, bv, bv, bv };
#pragma unroll
        for (int kq = 0; kq < 2; ++kq) {
            half8 bfv = *(const half8*)(B3 + kq * 32);
            acc = __builtin_amdgcn_mfma_f32_16x16x32_f16(af[kq], bfv, acc, 0, 0, 0);
        }
#pragma unroll
        for (int reg = 0; reg < 4; ++reg) {
            int b = brow + m0 + lq * 4 + reg;
            e3p[((long)e * 2048 + b) * 16 + l15] = acc[reg];
        }
    }
}

// ---------------------------------------------------------------------------
// Kernel 6: combine.  out[b][c] = sum_e probs[b][e] * e3p[e][b][c]
// ---------------------------------------------------------------------------
__global__ __launch_bounds__(256) void k_combine(
    const float* __restrict__ e3p, const float* __restrict__ probs,
    float* __restrict__ out)
{
    int t = blockIdx.x * blockDim.x + threadIdx.x;
    if (t >= 2048 * 10) return;
    int b = t / 10, c = t % 10;
    float acc = 0.f;
#pragma unroll
    for (int e = 0; e < 16; ++e)
        acc += probs[(long)b * 16 + e] * e3p[((long)e * 2048 + b) * 16 + c];
    out[t] = acc;
}

// ---------------------------------------------------------------------------
extern "C" void kernel_launch(void* const* d_in, const int* in_sizes, int n_in,
                              void* d_out, int out_size, void* d_ws, size_t ws_size,
                              hipStream_t stream)
{
    const float* x    = (const float*)d_in[0];
    const float* cW1  = (const float*)d_in[1];
    const float* cb1  = (const float*)d_in[2];
    const float* bn1g = (const float*)d_in[3];
    const float* bn1b = (const float*)d_in[4];
    const float* bn1m = (const float*)d_in[5];
    const float* bn1v = (const float*)d_in[6];
    const float* cW2  = (const float*)d_in[7];
    const float* cb2  = (const float*)d_in[8];
    const float* bn2g = (const float*)d_in[9];
    const float* bn2b = (const float*)d_in[10];
    const float* bn2m = (const float*)d_in[11];
    const float* bn2v = (const float*)d_in[12];
    const float* dW   = (const float*)d_in[13];
    const float* db   = (const float*)d_in[14];
    const float* rW1  = (const float*)d_in[15];
    const float* rb1  = (const float*)d_in[16];
    const float* rW2  = (const float*)d_in[17];
    const float* rb2  = (const float*)d_in[18];
    const float* eW1  = (const float*)d_in[19];
    const float* eb1  = (const float*)d_in[20];
    const float* ebng = (const float*)d_in[21];
    const float* ebnb = (const float*)d_in[22];
    const float* ebnm = (const float*)d_in[23];
    const float* ebnv = (const float*)d_in[24];
    const float* eW2  = (const float*)d_in[25];
    const float* eb2  = (const float*)d_in[26];
    const float* eW3  = (const float*)d_in[27];
    const float* eb3  = (const float*)d_in[28];

    float* ws    = (float*)d_ws;
    // --- region 1 (recycled): e3p + featsH ---
    float* h1reg = ws;
    float* e3p   = h1reg;                                  // [0 .. 524,288) floats
    _Float16* featsH = (_Float16*)(h1reg + 524288);        // 262,144 f16
    // --- region 2: h2reg ---
    float* h2reg = h1reg + 16777216;
    _Float16* h2f = (_Float16*)h2reg;                      // conv2 out f16 [2048][4096]
    _Float16* Wt2 = (_Float16*)(h2reg + 4194304);          // dense weights f16 [128][4096]
    // --- region 3: small tensors ---
    float* probs = h2reg + 8388608;
    float* ewreg = probs + 32768;
    _Float16* eW1t = (_Float16*)ewreg;             // 262,144 f16
    _Float16* eW2t = eW1t + 262144;                // 131,072 f16
    _Float16* eW3p = eW2t + 131072;                //  16,384 f16
    _Float16* Wt   = eW3p + 16384;                 //  18,432 f16 (conv2 w)
    _Float16* Wt1  = Wt + 18432;                   //   3,072 f16 slot (conv1 w)
    // --- region 4: dense split-K partials f16 [8][2048][128] = 4 MB ---
    _Float16* pws = (_Float16*)(ewreg + 262144);
    float* out   = (float*)d_out;

    k_wprep_all<<<244, 256, 0, stream>>>(dW, Wt2, eW1, eW1t, eW2, eW2t,
                                         cW1, Wt1, cW2, Wt, eW3, eW3p);
    k_conv12<<<1024, 256, 0, stream>>>(x, Wt1, cb1, bn1g, bn1b, bn1m, bn1v,
                                       Wt, cb2, bn2g, bn2b, bn2m, bn2v, h2f);
    {
        dim3 grid(128, 8);
        k_dense_mfma<<<grid, 256, 0, stream>>>(h2f, Wt2, pws);
    }
    k_reduce_router<<<256, 256, 0, stream>>>(pws, db, rW1, rb1, rW2, rb2,
                                             featsH, probs);
    {
        dim3 grid(16, 32);
        k_expert_mfma<<<grid, 512, 0, stream>>>(featsH, eW1t, eb1, ebng, ebnb, ebnm, ebnv,
                                                eW2t, eb2, eW3p, eb3, e3p);
    }
    k_combine<<<80, 256, 0, stream>>>(e3p, probs, out);
}